// Round 6
// baseline (1486.338 us; speedup 1.0000x reference)
//
#include <hip/hip_runtime.h>
#include <cstdint>
#include <cstddef>
#include <cmath>

#define B_     8192
#define XD_    4096
#define ZD_    1024
#define XE_    64
#define H_     128
#define ZN_    (B_*ZD_)

typedef __attribute__((ext_vector_type(8))) short short8_t;   // 8 x bf16 (4 VGPR)
typedef __attribute__((ext_vector_type(4))) float f32x4_t;    // MFMA accumulator
#define MFMA16(a,b,c) __builtin_amdgcn_mfma_f32_16x16x32_bf16((a),(b),(c),0,0,0)

// ---------------- threefry2x32 (bit-exact vs JAX, partitionable mode — validated R1/R2) ----
__host__ __device__ __forceinline__ uint32_t rotl32_(uint32_t x, int r){ return (x<<r)|(x>>(32-r)); }

__host__ __device__ __forceinline__ void tf2x32(uint32_t k0, uint32_t k1,
                                                uint32_t x0, uint32_t x1,
                                                uint32_t* o0, uint32_t* o1){
  uint32_t k2 = k0 ^ k1 ^ 0x1BD11BDAu;
  x0 += k0; x1 += k1;
  x0 += x1; x1 = rotl32_(x1,13); x1 ^= x0;
  x0 += x1; x1 = rotl32_(x1,15); x1 ^= x0;
  x0 += x1; x1 = rotl32_(x1,26); x1 ^= x0;
  x0 += x1; x1 = rotl32_(x1, 6); x1 ^= x0;
  x0 += k1; x1 += k2 + 1u;
  x0 += x1; x1 = rotl32_(x1,17); x1 ^= x0;
  x0 += x1; x1 = rotl32_(x1,29); x1 ^= x0;
  x0 += x1; x1 = rotl32_(x1,16); x1 ^= x0;
  x0 += x1; x1 = rotl32_(x1,24); x1 ^= x0;
  x0 += k2; x1 += k0 + 2u;
  x0 += x1; x1 = rotl32_(x1,13); x1 ^= x0;
  x0 += x1; x1 = rotl32_(x1,15); x1 ^= x0;
  x0 += x1; x1 = rotl32_(x1,26); x1 ^= x0;
  x0 += x1; x1 = rotl32_(x1, 6); x1 ^= x0;
  x0 += k0; x1 += k1 + 3u;
  x0 += x1; x1 = rotl32_(x1,17); x1 ^= x0;
  x0 += x1; x1 = rotl32_(x1,29); x1 ^= x0;
  x0 += x1; x1 = rotl32_(x1,16); x1 ^= x0;
  x0 += x1; x1 = rotl32_(x1,24); x1 ^= x0;
  x0 += k1; x1 += k2 + 4u;
  x0 += x1; x1 = rotl32_(x1,13); x1 ^= x0;
  x0 += x1; x1 = rotl32_(x1,15); x1 ^= x0;
  x0 += x1; x1 = rotl32_(x1,26); x1 ^= x0;
  x0 += x1; x1 = rotl32_(x1, 6); x1 ^= x0;
  x0 += k2; x1 += k0 + 5u;
  *o0 = x0; *o1 = x1;
}

__device__ __forceinline__ float erfinv_(float x){
  float w = -log1pf(-x*x);
  float p;
  if (w < 5.0f){
    w -= 2.5f;
    p = 2.81022636e-08f;
    p = fmaf(p, w, 3.43273939e-07f);
    p = fmaf(p, w, -3.5233877e-06f);
    p = fmaf(p, w, -4.39150654e-06f);
    p = fmaf(p, w, 0.00021858087f);
    p = fmaf(p, w, -0.00125372503f);
    p = fmaf(p, w, -0.00417768164f);
    p = fmaf(p, w, 0.246640727f);
    p = fmaf(p, w, 1.50140941f);
  } else {
    w = sqrtf(w) - 3.0f;
    p = -0.000200214257f;
    p = fmaf(p, w, 0.000100950558f);
    p = fmaf(p, w, 0.00134934322f);
    p = fmaf(p, w, -0.00367342844f);
    p = fmaf(p, w, 0.00573950773f);
    p = fmaf(p, w, -0.0076224613f);
    p = fmaf(p, w, 0.00943887047f);
    p = fmaf(p, w, 1.00167406f);
    p = fmaf(p, w, 2.83297682f);
  }
  return p * x;
}

__device__ __forceinline__ float bits_to_normal(uint32_t bits){
  float f = __uint_as_float((bits >> 9) | 0x3f800000u) - 1.0f;
  float u = fmaxf(-0.99999994f, fmaf(f, 2.0f, -0.99999994f));
  return 1.41421356f * erfinv_(u);
}

__device__ __forceinline__ float rng_normal(uint32_t k0, uint32_t k1, uint32_t idx){
  uint32_t o0, o1; tf2x32(k0, k1, 0u, idx, &o0, &o1);
  return bits_to_normal(o0 ^ o1);
}

__device__ __forceinline__ ushort f2bf(float f){
  uint32_t u = __float_as_uint(f);
  return (ushort)((u + 0x7FFFu + ((u >> 16) & 1u)) >> 16);
}
__device__ __forceinline__ float bf2f(ushort u){ return __uint_as_float(((uint32_t)u) << 16); }

// ---------------- weight-prep kernels (f32) ----------------
__global__ void k_prepA(const float* __restrict__ saWo, const float* __restrict__ saWqkv,
                        const float* __restrict__ caWo, const float* __restrict__ caWqkv,
                        float* __restrict__ S, float* __restrict__ U){
  int blk = blockIdx.x, tid = threadIdx.x;
  int idx = (blk & 255) * 64 + tid;
  int i = idx >> 7, j = idx & 127;
  if (blk < 256){
    float acc = (i == j) ? 1.0f : 0.0f;
    for (int k = 0; k < H_; ++k) acc += saWo[i*H_ + k] * saWqkv[(2*H_ + k)*H_ + j];
    S[idx] = acc;
  } else {
    float acc = 0.0f;
    for (int k = 0; k < H_; ++k) acc += caWo[i*H_ + k] * caWqkv[(2*H_ + k)*H_ + j];
    U[idx] = acc;
  }
}

__global__ void k_prepB(const float* __restrict__ saWo, const float* __restrict__ sabqkv, const float* __restrict__ sabo,
                        const float* __restrict__ caWo, const float* __restrict__ cabqkv, const float* __restrict__ cabo,
                        const float* __restrict__ W2, const float* __restrict__ pb2,
                        float* __restrict__ s0, float* __restrict__ u0, float* __restrict__ cb,
                        uint32_t* __restrict__ dkeys){
  int blk = blockIdx.x, tid = threadIdx.x;
  if (blk == 0 && tid == 0){
    for (uint32_t i = 0; i < 11; ++i){
      uint32_t a, b; tf2x32(0u, 42u, 0u, i, &a, &b);
      dkeys[2*i] = a; dkeys[2*i+1] = b;
    }
  }
  if (blk < 2){
    int i = blk*64 + tid;
    float acc = sabo[i];
    for (int k = 0; k < H_; ++k) acc += saWo[i*H_ + k] * sabqkv[2*H_ + k];
    s0[i] = acc;
  } else if (blk < 4){
    int i = (blk-2)*64 + tid;
    float acc = cabo[i];
    for (int k = 0; k < H_; ++k) acc += caWo[i*H_ + k] * cabqkv[2*H_ + k];
    u0[i] = acc;
  } else {
    int j = (blk-4)*64 + tid;
    float acc = 0.0f;
    for (int c = 0; c < XD_; ++c) acc += pb2[c] * W2[(size_t)c*H_ + j];
    cb[j] = acc;
  }
}

__global__ void k_prepM(const float* __restrict__ W2, float* __restrict__ M){
  int idx = blockIdx.x*64 + threadIdx.x;  // 16384
  int j1 = idx >> 7, j2 = idx & 127;
  float acc = 0.0f;
  for (int c = 0; c < XD_; ++c) acc += W2[(size_t)c*H_ + j1] * W2[(size_t)c*H_ + j2];
  M[idx] = acc;
}

__global__ void k_prepTR(const float* __restrict__ S, const float* __restrict__ U,
                         const float* __restrict__ xpW, const float* __restrict__ zpW,
                         const float* __restrict__ xpb, const float* __restrict__ zpb,
                         const float* __restrict__ s0, const float* __restrict__ u0,
                         float* __restrict__ T, float* __restrict__ R,
                         float* __restrict__ t0, float* __restrict__ r0v){
  int blk = blockIdx.x, tid = threadIdx.x;
  if (blk < 128){
    int idx = blk*64 + tid;
    int i = idx >> 6, e = idx & 63;
    float acc = 0.0f;
    for (int m = 0; m < H_; ++m) acc += S[i*H_ + m] * xpW[m*XE_ + e];
    T[idx] = acc;
  } else if (blk < 2176){
    int idx = (blk-128)*64 + tid;
    int i = idx >> 10, k = idx & 1023;
    float acc = 0.0f;
    for (int m = 0; m < H_; ++m) acc += U[i*H_ + m] * zpW[(size_t)m*ZD_ + k];
    R[idx] = acc;
  } else if (blk < 2178){
    int i = (blk-2176)*64 + tid;
    float acc = s0[i];
    for (int m = 0; m < H_; ++m) acc += S[i*H_ + m] * xpb[m];
    t0[i] = acc;
  } else {
    int i = (blk-2178)*64 + tid;
    float acc = u0[i];
    for (int m = 0; m < H_; ++m) acc += U[i*H_ + m] * zpb[m];
    r0v[i] = acc;
  }
}

__global__ void k_prepWXT(const float* __restrict__ W2, const float* __restrict__ T,
                          const float* __restrict__ embW, const float* __restrict__ embb,
                          const float* __restrict__ t0,
                          ushort* __restrict__ WXT, float* __restrict__ q0){
  int idx = blockIdx.x*256 + threadIdx.x;   // 1048576
  int j = idx >> 12, c = idx & 4095;
  float v;
  if (j < H_) v = W2[(size_t)c*H_ + j];
  else {
    int i = j - H_;
    float acc = 0.0f;
    for (int e = 0; e < XE_; ++e) acc += T[i*XE_ + e] * embW[(size_t)e*XD_ + c];
    v = acc;
  }
  WXT[idx] = f2bf(v);
  if (idx < H_){
    float acc = t0[idx];
    for (int e = 0; e < XE_; ++e) acc += T[idx*XE_ + e] * embb[e];
    q0[idx] = acc;
  }
}

__global__ void k_conv(const float* __restrict__ W2, const float* __restrict__ W1,
                       const float* __restrict__ Mm, const float* __restrict__ R,
                       ushort* __restrict__ W2bf, ushort* __restrict__ W1bf,
                       ushort* __restrict__ W1Tbf, ushort* __restrict__ Mbf,
                       ushort* __restrict__ FBT){
  int idx = blockIdx.x*256 + threadIdx.x;   // 1064960
  if (idx < 524288) W2bf[idx] = f2bf(W2[idx]);
  else if (idx < 655360){ int i = idx - 524288; W1bf[i] = f2bf(W1[i]); }
  else if (idx < 786432){ int i = idx - 655360; int k = i >> 7, h = i & 127;
    W1Tbf[i] = f2bf(W1[h*ZD_ + k]); }
  else if (idx < 802816){ int i = idx - 786432; Mbf[i] = f2bf(Mm[i]); }
  else { int i = idx - 802816; int j = i >> 10, k = i & 1023;
    FBT[i] = f2bf(j < H_ ? W1[j*ZD_ + k] : R[(size_t)(j-H_)*ZD_ + k]); }
}

// ---------------- x-pass (MFMA, dbuf, 1 barrier/iter): [cneg | h1pre] = x @ WXT^T ----
// BM=32, BN=128, grid 512, 256 thr.
__global__ __launch_bounds__(256) void k_xpass_mfma(
    const float* __restrict__ x, const ushort* __restrict__ WXT,
    const float* __restrict__ cb, const float* __restrict__ q0,
    float* __restrict__ cneg, float* __restrict__ h1pre){
  __shared__ __align__(16) ushort xt[2][32*72];
  __shared__ __align__(16) ushort bt[2][128*72];
  const int t = threadIdx.x, lane = t & 63, w = t >> 6;
  const int bm = blockIdx.x >> 1, bn = blockIdx.x & 1;
  const int row0 = bm*32, ncol0 = bn*128;
  const int l15 = lane & 15, kq8 = (lane >> 4)*8, rq = (lane >> 4)*4;
  const int rt = w & 1, cb4 = (w >> 1)*4;
  const int xr = t >> 3, xk = (t & 7)*8;
  const int wn = t >> 1, wk = (t & 1)*32;
  f32x4_t acc[4] = {};
  // prologue: stage tile 0
  {
    float4 v0 = *(const float4*)&x[(size_t)(row0+xr)*XD_ + xk];
    float4 v1 = *(const float4*)&x[(size_t)(row0+xr)*XD_ + xk + 4];
    union { ushort u[8]; uint4 q; } p;
    p.u[0]=f2bf(v0.x); p.u[1]=f2bf(v0.y); p.u[2]=f2bf(v0.z); p.u[3]=f2bf(v0.w);
    p.u[4]=f2bf(v1.x); p.u[5]=f2bf(v1.y); p.u[6]=f2bf(v1.z); p.u[7]=f2bf(v1.w);
    *(uint4*)&xt[0][xr*72 + xk] = p.q;
    const ushort* s = &WXT[(size_t)(ncol0+wn)*XD_ + wk];
    uint4 b0v=*(const uint4*)s, b1v=*(const uint4*)(s+8), b2v=*(const uint4*)(s+16), b3v=*(const uint4*)(s+24);
    ushort* d = &bt[0][wn*72 + wk];
    *(uint4*)d=b0v; *(uint4*)(d+8)=b1v; *(uint4*)(d+16)=b2v; *(uint4*)(d+24)=b3v;
  }
  for (int it = 0; it < 64; ++it){
    const int cur = it & 1;
    float4 v0, v1; uint4 b0v, b1v, b2v, b3v;
    if (it < 63){
      const int kt = (it+1)*64;
      v0 = *(const float4*)&x[(size_t)(row0+xr)*XD_ + kt + xk];
      v1 = *(const float4*)&x[(size_t)(row0+xr)*XD_ + kt + xk + 4];
      const ushort* s = &WXT[(size_t)(ncol0+wn)*XD_ + kt + wk];
      b0v=*(const uint4*)s; b1v=*(const uint4*)(s+8); b2v=*(const uint4*)(s+16); b3v=*(const uint4*)(s+24);
    }
    __syncthreads();
    #pragma unroll
    for (int h = 0; h < 2; ++h){
      short8_t a = *(const short8_t*)&xt[cur][(rt*16+l15)*72 + h*32 + kq8];
      #pragma unroll
      for (int c = 0; c < 4; ++c){
        short8_t b = *(const short8_t*)&bt[cur][((cb4+c)*16+l15)*72 + h*32 + kq8];
        acc[c] = MFMA16(a, b, acc[c]);
      }
    }
    if (it < 63){
      const int nxt = cur ^ 1;
      union { ushort u[8]; uint4 q; } p;
      p.u[0]=f2bf(v0.x); p.u[1]=f2bf(v0.y); p.u[2]=f2bf(v0.z); p.u[3]=f2bf(v0.w);
      p.u[4]=f2bf(v1.x); p.u[5]=f2bf(v1.y); p.u[6]=f2bf(v1.z); p.u[7]=f2bf(v1.w);
      *(uint4*)&xt[nxt][xr*72 + xk] = p.q;
      ushort* d = &bt[nxt][wn*72 + wk];
      *(uint4*)d=b0v; *(uint4*)(d+8)=b1v; *(uint4*)(d+16)=b2v; *(uint4*)(d+24)=b3v;
    }
  }
  #pragma unroll
  for (int c = 0; c < 4; ++c){
    int jl = (cb4+c)*16 + l15;
    #pragma unroll
    for (int r = 0; r < 4; ++r){
      int row = row0 + rt*16 + rq + r;
      float v = acc[c][r];
      if (bn == 0) cneg[(size_t)row*H_ + jl] = 2.0f*(cb[jl] - v);
      else         h1pre[(size_t)row*H_ + jl] = v + q0[jl];
    }
  }
}

// ---------------- fused Langevin: init + 10 steps + finalz; z lives in VGPRs ----------
// grid 512 blocks x 512 thr (8 waves). BM=16 rows/block.
// __launch_bounds__ 2nd arg is MIN BLOCKS PER CU (CUDA semantics — established
// empirically R3/R4/R5: (512,4)->64 VGPR, (512,2)->128, plain (512) defaults to
// 2-block target ->128, all spill). (512,1) + amdgpu_waves_per_eu(2) pins
// 1 block = 8 waves/CU = 2 waves/SIMD -> 256 VGPR cap. Kernel needs ~150-190.
__global__ __launch_bounds__(512, 1) __attribute__((amdgpu_waves_per_eu(2)))
void k_langevin(
    const ushort* __restrict__ W1bf, const ushort* __restrict__ W1Tbf,
    const ushort* __restrict__ Mbf, const ushort* __restrict__ FBT,
    const float* __restrict__ b1, const float* __restrict__ r0v,
    const float* __restrict__ cneg, const uint32_t* __restrict__ dkeys,
    ushort* __restrict__ hfin_bf, float* __restrict__ capre){
  __shared__ __align__(16) ushort as_[2][16*72];
  __shared__ __align__(16) ushort ws_[2][128*72];
  __shared__ __align__(16) ushort abuf[16*136];
  __shared__ __align__(16) ushort glbuf[16*136];

  const int t = threadIdx.x, lane = t & 63, w = t >> 6;
  const int l15 = lane & 15, kq8 = (lane >> 4)*8, rq = (lane >> 4)*4;
  const int b0 = blockIdx.x * 16;
  const int row16 = t >> 5, c32 = t & 31, qc = c32*4;
  const int myc = w*16 + l15;

  // ---- z0 init (RNG) into registers
  float4 zr[8];
  {
    const uint32_t k0 = dkeys[0], k1 = dkeys[1];
    #pragma unroll
    for (int i = 0; i < 8; ++i){
      uint32_t base = (uint32_t)(b0 + row16)*1024u + (uint32_t)(qc + 128*i);
      zr[i].x = rng_normal(k0,k1,base+0);
      zr[i].y = rng_normal(k0,k1,base+1);
      zr[i].z = rng_normal(k0,k1,base+2);
      zr[i].w = rng_normal(k0,k1,base+3);
    }
  }
  const float bb = b1[myc];
  float cn[4];
  #pragma unroll
  for (int r = 0; r < 4; ++r) cn[r] = cneg[(size_t)(b0+rq+r)*H_ + myc];

  for (int s = 0; s < 10; ++s){
    const uint32_t nk0 = dkeys[2+2*s], nk1 = dkeys[3+2*s];
    // ---------- P1: h = z @ W1^T  (K=1024, dbuf, 1 barrier/iter)
    f32x4_t acc = {};
    {
      if ((c32 >> 4) == 0){
        float4 v = zr[0];
        union { ushort u[4]; uint2 q2; } p;
        p.u[0]=f2bf(v.x); p.u[1]=f2bf(v.y); p.u[2]=f2bf(v.z); p.u[3]=f2bf(v.w);
        *(uint2*)&as_[0][row16*72 + (c32&15)*4] = p.q2;
      }
      const ushort* sw = &W1bf[(size_t)(t>>2)*ZD_ + (t&3)*16];
      uint4 a0 = *(const uint4*)sw, a1 = *(const uint4*)(sw+8);
      ushort* d = &ws_[0][(t>>2)*72 + (t&3)*16];
      *(uint4*)d = a0; *(uint4*)(d+8) = a1;
    }
    #pragma unroll
    for (int it = 0; it < 16; ++it){
      const int cur = it & 1;
      uint4 a0, a1;
      if (it < 15){
        const ushort* sw = &W1bf[(size_t)(t>>2)*ZD_ + (it+1)*64 + (t&3)*16];
        a0 = *(const uint4*)sw; a1 = *(const uint4*)(sw+8);
      }
      __syncthreads();
      #pragma unroll
      for (int h = 0; h < 2; ++h){
        short8_t av = *(const short8_t*)&as_[cur][l15*72 + h*32 + kq8];
        short8_t bv = *(const short8_t*)&ws_[cur][myc*72 + h*32 + kq8];
        acc = MFMA16(av, bv, acc);
      }
      if (it < 15){
        const int nxt = cur ^ 1;
        if ((c32 >> 4) == ((it+1) & 1)){
          float4 v = zr[(it+1) >> 1];
          union { ushort u[4]; uint2 q2; } p;
          p.u[0]=f2bf(v.x); p.u[1]=f2bf(v.y); p.u[2]=f2bf(v.z); p.u[3]=f2bf(v.w);
          *(uint2*)&as_[nxt][row16*72 + (c32&15)*4] = p.q2;
        }
        ushort* d = &ws_[nxt][(t>>2)*72 + (t&3)*16];
        *(uint4*)d = a0; *(uint4*)(d+8) = a1;
      }
    }
    float hv[4];
    #pragma unroll
    for (int r = 0; r < 4; ++r){
      hv[r] = acc[r] + bb;
      abuf[(rq+r)*136 + myc] = f2bf(hv[r] > 0.f ? hv[r] : 0.f);
    }
    __syncthreads();           // abuf ready; P1 ws reads done
    // ---------- stage M into ws_[0]/ws_[1]
    {
      const int n = t >> 2, kk = (t & 3)*32;
      const ushort* sm = &Mbf[(size_t)n*H_ + kk];
      uint4 m0=*(const uint4*)sm, m1=*(const uint4*)(sm+8), m2=*(const uint4*)(sm+16), m3=*(const uint4*)(sm+24);
      ushort* d = &ws_[kk>>6][n*72 + (kk&63)];
      *(uint4*)d=m0; *(uint4*)(d+8)=m1; *(uint4*)(d+16)=m2; *(uint4*)(d+24)=m3;
    }
    __syncthreads();
    // ---------- P2: g2 = a @ M
    f32x4_t acc2 = {};
    #pragma unroll
    for (int c = 0; c < 2; ++c)
      #pragma unroll
      for (int h = 0; h < 2; ++h){
        short8_t av = *(const short8_t*)&abuf[l15*136 + c*64 + h*32 + kq8];
        short8_t bv = *(const short8_t*)&ws_[c][myc*72 + h*32 + kq8];
        acc2 = MFMA16(av, bv, acc2);
      }
    #pragma unroll
    for (int r = 0; r < 4; ++r){
      float g = (hv[r] > 0.f) ? fmaf(2.f, acc2[r], cn[r]) : 0.f;
      glbuf[(rq+r)*136 + myc] = f2bf(g);
    }
    __syncthreads();           // glbuf ready; M reads done
    // ---------- P3: z -= hstep*(g @ W1) + noise ; 8 n-tiles, 2 barriers/tile
    #pragma unroll
    for (int nt = 0; nt < 8; ++nt){
      const int n = t >> 2, kk = (t & 3)*32;
      const ushort* sw = &W1Tbf[(size_t)(nt*128 + n)*H_ + kk];
      uint4 v0=*(const uint4*)sw, v1=*(const uint4*)(sw+8), v2=*(const uint4*)(sw+16), v3=*(const uint4*)(sw+24);
      __syncthreads();         // delta(nt-1) visible; prev MFMA ws reads done
      if (nt > 0){
        ushort4 dd = *(const ushort4*)&abuf[row16*136 + qc];
        uint32_t base = (uint32_t)(b0+row16)*1024u + (uint32_t)((nt-1)*128 + qc);
        float4 zz = zr[nt-1];
        zz.x = fmaf(0.1f, rng_normal(nk0,nk1,base+0), fmaf(-0.005f, bf2f(dd.x), zz.x));
        zz.y = fmaf(0.1f, rng_normal(nk0,nk1,base+1), fmaf(-0.005f, bf2f(dd.y), zz.y));
        zz.z = fmaf(0.1f, rng_normal(nk0,nk1,base+2), fmaf(-0.005f, bf2f(dd.z), zz.z));
        zz.w = fmaf(0.1f, rng_normal(nk0,nk1,base+3), fmaf(-0.005f, bf2f(dd.w), zz.w));
        zr[nt-1] = zz;
      }
      {
        ushort* d = &ws_[kk>>6][n*72 + (kk&63)];
        *(uint4*)d=v0; *(uint4*)(d+8)=v1; *(uint4*)(d+16)=v2; *(uint4*)(d+24)=v3;
      }
      __syncthreads();         // ws ready; owner reads(nt-1) done
      f32x4_t acc3 = {};
      #pragma unroll
      for (int c = 0; c < 2; ++c)
        #pragma unroll
        for (int h = 0; h < 2; ++h){
          short8_t av = *(const short8_t*)&glbuf[l15*136 + c*64 + h*32 + kq8];
          short8_t bv = *(const short8_t*)&ws_[c][myc*72 + h*32 + kq8];
          acc3 = MFMA16(av, bv, acc3);
        }
      #pragma unroll
      for (int r = 0; r < 4; ++r) abuf[(rq+r)*136 + myc] = f2bf(acc3[r]);
    }
    __syncthreads();
    {                          // owner update for nt=7
      ushort4 dd = *(const ushort4*)&abuf[row16*136 + qc];
      uint32_t base = (uint32_t)(b0+row16)*1024u + (uint32_t)(7*128 + qc);
      float4 zz = zr[7];
      zz.x = fmaf(0.1f, rng_normal(nk0,nk1,base+0), fmaf(-0.005f, bf2f(dd.x), zz.x));
      zz.y = fmaf(0.1f, rng_normal(nk0,nk1,base+1), fmaf(-0.005f, bf2f(dd.y), zz.y));
      zz.z = fmaf(0.1f, rng_normal(nk0,nk1,base+2), fmaf(-0.005f, bf2f(dd.z), zz.z));
      zz.w = fmaf(0.1f, rng_normal(nk0,nk1,base+3), fmaf(-0.005f, bf2f(dd.w), zz.w));
      zr[7] = zz;
    }
  }

  // ---------- finalz: [hfin | capre] = z @ FBT^T  (K=1024, N=256)
  f32x4_t fac0 = {}, fac1 = {};
  #pragma unroll
  for (int it = 0; it < 16; ++it){
    const int n2 = t >> 1, kh = (t & 1)*32;
    const ushort* sf = &FBT[(size_t)n2*ZD_ + it*64 + kh];
    uint4 f0=*(const uint4*)sf, f1=*(const uint4*)(sf+8), f2v=*(const uint4*)(sf+16), f3=*(const uint4*)(sf+24);
    __syncthreads();           // prev iter MFMA reads done
    if ((c32 >> 4) == (it & 1)){
      float4 v = zr[it >> 1];
      union { ushort u[4]; uint2 q2; } p;
      p.u[0]=f2bf(v.x); p.u[1]=f2bf(v.y); p.u[2]=f2bf(v.z); p.u[3]=f2bf(v.w);
      *(uint2*)&as_[0][row16*72 + (c32&15)*4] = p.q2;
    }
    {
      ushort* d = (n2 < 128) ? &ws_[0][n2*72 + kh] : &ws_[1][(n2-128)*72 + kh];
      *(uint4*)d=f0; *(uint4*)(d+8)=f1; *(uint4*)(d+16)=f2v; *(uint4*)(d+24)=f3;
    }
    __syncthreads();
    #pragma unroll
    for (int h = 0; h < 2; ++h){
      short8_t av = *(const short8_t*)&as_[0][l15*72 + h*32 + kq8];
      short8_t bv0 = *(const short8_t*)&ws_[0][myc*72 + h*32 + kq8];
      fac0 = MFMA16(av, bv0, fac0);
      short8_t bv1 = *(const short8_t*)&ws_[1][myc*72 + h*32 + kq8];
      fac1 = MFMA16(av, bv1, fac1);
    }
  }
  {
    const float rv = r0v[myc];
    #pragma unroll
    for (int r = 0; r < 4; ++r){
      int row = b0 + rq + r;
      float h0 = fac0[r] + bb;
      hfin_bf[(size_t)row*H_ + myc] = f2bf(h0 > 0.f ? h0 : 0.f);
      capre[(size_t)row*H_ + myc] = fac1[r] + rv;
    }
  }
}

// ---------------- x_recon (MFMA): out = hfin @ W2^T + b2 ----------------
__global__ __launch_bounds__(256) void k_xrecon_mfma(
    const ushort* __restrict__ hfin_bf, const ushort* __restrict__ W2bf,
    const float* __restrict__ b2, float* __restrict__ out){
  __shared__ __align__(16) ushort at[64*136];
  __shared__ __align__(16) ushort bt[128*136];
  const int tid = threadIdx.x, lane = tid & 63, w = tid >> 6;
  const int bm = blockIdx.x >> 5, bn = blockIdx.x & 31;
  const int row0 = bm*64, c0 = bn*128;
  const int l15 = lane & 15, kq8 = (lane >> 4)*8, rq = (lane >> 4)*4;
  { int r = tid >> 2, kq = (tid & 3)*32;
    const ushort* src = &hfin_bf[(size_t)(row0 + r)*H_ + kq];
    #pragma unroll
    for (int i = 0; i < 4; ++i) *(uint4*)&at[r*136 + kq + 8*i] = *(const uint4*)(src + 8*i);
  }
  { int n = tid >> 1, kh = (tid & 1)*64;
    const ushort* src = &W2bf[(size_t)(c0 + n)*H_ + kh];
    #pragma unroll
    for (int i = 0; i < 8; ++i) *(uint4*)&bt[n*136 + kh + 8*i] = *(const uint4*)(src + 8*i);
  }
  __syncthreads();
  f32x4_t acc[8] = {};
  #pragma unroll
  for (int k = 0; k < 4; ++k){
    short8_t a = *(const short8_t*)&at[(w*16 + l15)*136 + k*32 + kq8];
    #pragma unroll
    for (int nf = 0; nf < 8; ++nf){
      short8_t b = *(const short8_t*)&bt[(nf*16 + l15)*136 + k*32 + kq8];
      acc[nf] = MFMA16(a, b, acc[nf]);
    }
  }
  #pragma unroll
  for (int nf = 0; nf < 8; ++nf){
    int c = c0 + nf*16 + l15;
    float bbv = b2[c];
    #pragma unroll
    for (int r = 0; r < 4; ++r){
      int row = row0 + w*16 + rq + r;
      out[(size_t)row*XD_ + c] = acc[nf][r] + bbv;
    }
  }
}

// ---------------- per-row transformer tail -> y_pred ----------------
__device__ __forceinline__ float wsum64(float v){
  #pragma unroll
  for (int off = 32; off > 0; off >>= 1) v += __shfl_xor(v, off, 64);
  return v;
}

__global__ __launch_bounds__(256) void k_tail(
    const float* __restrict__ h1pre, const float* __restrict__ capre,
    const float* __restrict__ ln1g, const float* __restrict__ ln1b,
    const float* __restrict__ ln2g, const float* __restrict__ ln2b,
    const float* __restrict__ ln3g, const float* __restrict__ ln3b,
    const float* __restrict__ fW1, const float* __restrict__ fb1,
    const float* __restrict__ fW2, const float* __restrict__ fb2,
    const float* __restrict__ outW, const float* __restrict__ outb,
    float* __restrict__ y){
  __shared__ float sh2[4][128];
  __shared__ float st1[4][128];
  const int tid = threadIdx.x;
  const int w = tid >> 6;
  const int l = tid & 63;
  const int b = blockIdx.x * 4 + w;
  const float* hp = h1pre + (size_t)b * H_;
  const float* cp = capre + (size_t)b * H_;
  float x0 = hp[l], x1 = hp[l+64];
  float m = wsum64(x0 + x1) * (1.0f/128.0f);
  float d0 = x0 - m, d1 = x1 - m;
  float v = wsum64(d0*d0 + d1*d1) * (1.0f/128.0f);
  float rs = rsqrtf(v + 1e-5f);
  float h1a = d0 * rs * ln1g[l]    + ln1b[l];
  float h1b = d1 * rs * ln1g[l+64] + ln1b[l+64];
  x0 = h1a + cp[l]; x1 = h1b + cp[l+64];
  m = wsum64(x0 + x1) * (1.0f/128.0f);
  d0 = x0 - m; d1 = x1 - m;
  v = wsum64(d0*d0 + d1*d1) * (1.0f/128.0f);
  rs = rsqrtf(v + 1e-5f);
  float h2a = d0 * rs * ln2g[l]    + ln2b[l];
  float h2b = d1 * rs * ln2g[l+64] + ln2b[l+64];
  sh2[w][l] = h2a; sh2[w][l+64] = h2b;
  __syncthreads();
  float ta = fb1[l], tb = fb1[l+64];
  #pragma unroll 8
  for (int m4 = 0; m4 < H_; m4 += 4){
    float4 hv = *(const float4*)&sh2[w][m4];
    float4 wa = *(const float4*)&fW1[(size_t)l*H_ + m4];
    float4 wb = *(const float4*)&fW1[(size_t)(l+64)*H_ + m4];
    ta = fmaf(wa.x, hv.x, ta); ta = fmaf(wa.y, hv.y, ta); ta = fmaf(wa.z, hv.z, ta); ta = fmaf(wa.w, hv.w, ta);
    tb = fmaf(wb.x, hv.x, tb); tb = fmaf(wb.y, hv.y, tb); tb = fmaf(wb.z, hv.z, tb); tb = fmaf(wb.w, hv.w, tb);
  }
  ta = fmaxf(ta, 0.0f); tb = fmaxf(tb, 0.0f);
  st1[w][l] = ta; st1[w][l+64] = tb;
  __syncthreads();
  float fa = fb2[l], fbv = fb2[l+64];
  #pragma unroll 8
  for (int m4 = 0; m4 < H_; m4 += 4){
    float4 tv = *(const float4*)&st1[w][m4];
    float4 wa = *(const float4*)&fW2[(size_t)l*H_ + m4];
    float4 wb = *(const float4*)&fW2[(size_t)(l+64)*H_ + m4];
    fa  = fmaf(wa.x, tv.x, fa);  fa  = fmaf(wa.y, tv.y, fa);  fa  = fmaf(wa.z, tv.z, fa);  fa  = fmaf(wa.w, tv.w, fa);
    fbv = fmaf(wb.x, tv.x, fbv); fbv = fmaf(wb.y, tv.y, fbv); fbv = fmaf(wb.z, tv.z, fbv); fbv = fmaf(wb.w, tv.w, fbv);
  }
  x0 = h2a + fa; x1 = h2b + fbv;
  m = wsum64(x0 + x1) * (1.0f/128.0f);
  d0 = x0 - m; d1 = x1 - m;
  v = wsum64(d0*d0 + d1*d1) * (1.0f/128.0f);
  rs = rsqrtf(v + 1e-5f);
  float h3a = d0 * rs * ln3g[l]    + ln3b[l];
  float h3b = d1 * rs * ln3g[l+64] + ln3b[l+64];
  float py = wsum64(outW[l]*h3a + outW[l+64]*h3b);
  if (l == 0) y[b] = py + outb[0];
}

// ---------------- host ----------------
extern "C" void kernel_launch(void* const* d_in, const int* in_sizes, int n_in,
                              void* d_out, int out_size, void* d_ws, size_t ws_size,
                              hipStream_t stream){
  const float* x      = (const float*)d_in[0];
  const float* pxW1   = (const float*)d_in[1];
  const float* pxb1   = (const float*)d_in[2];
  const float* pxW2   = (const float*)d_in[3];
  const float* pxb2   = (const float*)d_in[4];
  const float* embW   = (const float*)d_in[5];
  const float* embb   = (const float*)d_in[6];
  const float* xpW    = (const float*)d_in[7];
  const float* xpb    = (const float*)d_in[8];
  const float* zpW    = (const float*)d_in[9];
  const float* zpb    = (const float*)d_in[10];
  const float* saWqkv = (const float*)d_in[11];
  const float* sabqkv = (const float*)d_in[12];
  const float* saWo   = (const float*)d_in[13];
  const float* sabo   = (const float*)d_in[14];
  const float* caWqkv = (const float*)d_in[15];
  const float* cabqkv = (const float*)d_in[16];
  const float* caWo   = (const float*)d_in[17];
  const float* cabo   = (const float*)d_in[18];
  const float* fW1    = (const float*)d_in[19];
  const float* fb1    = (const float*)d_in[20];
  const float* fW2    = (const float*)d_in[21];
  const float* fb2    = (const float*)d_in[22];
  const float* ln1g   = (const float*)d_in[23];
  const float* ln1b   = (const float*)d_in[24];
  const float* ln2g   = (const float*)d_in[25];
  const float* ln2b   = (const float*)d_in[26];
  const float* ln3g   = (const float*)d_in[27];
  const float* ln3b   = (const float*)d_in[28];
  const float* outW   = (const float*)d_in[29];
  const float* outb   = (const float*)d_in[30];
  (void)in_sizes; (void)n_in; (void)out_size; (void)ws_size;

  float* ws    = (float*)d_ws;
  float* cneg  = ws;                          // 1048576
  float* h1pre = cneg + (size_t)B_*H_;        // 1048576
  float* capre = h1pre + (size_t)B_*H_;       // 1048576
  float* Rm    = capre + (size_t)B_*H_;       // 131072
  float* Mm    = Rm + (size_t)H_*ZD_;         // 16384
  float* Sm    = Mm + H_*H_;                  // 16384
  float* Um    = Sm + H_*H_;                  // 16384
  float* Tm    = Um + H_*H_;                  // 8192
  float* vs0   = Tm + H_*XE_;
  float* vu0   = vs0 + H_;
  float* vt0   = vu0 + H_;
  float* vq0   = vt0 + H_;
  float* vr0   = vq0 + H_;
  float* vcb   = vr0 + H_;
  uint32_t* dkeys = (uint32_t*)(vcb + H_);    // 32 u32
  ushort* WXT   = (ushort*)(dkeys + 32);      // 1048576
  ushort* W2bf  = WXT + (size_t)256*XD_;      // 524288
  ushort* W1bf  = W2bf + (size_t)XD_*H_;      // 131072
  ushort* W1Tbf = W1bf + (size_t)H_*ZD_;      // 131072
  ushort* Mbf   = W1Tbf + (size_t)ZD_*H_;     // 16384
  ushort* FBT   = Mbf + H_*H_;                // 262144
  ushort* hfin  = FBT + (size_t)256*ZD_;      // 1048576

  float* xre   = (float*)d_out;
  float* ypred = xre + (size_t)B_*XD_;

  k_prepA   <<<512,  64, 0, stream>>>(saWo, saWqkv, caWo, caWqkv, Sm, Um);
  k_prepB   <<<6,    64, 0, stream>>>(saWo, sabqkv, sabo, caWo, cabqkv, cabo, pxW2, pxb2,
                                      vs0, vu0, vcb, dkeys);
  k_prepM   <<<256,  64, 0, stream>>>(pxW2, Mm);
  k_prepTR  <<<2180, 64, 0, stream>>>(Sm, Um, xpW, zpW, xpb, zpb, vs0, vu0, Tm, Rm, vt0, vr0);
  k_prepWXT <<<4096, 256, 0, stream>>>(pxW2, Tm, embW, embb, vt0, WXT, vq0);
  k_conv    <<<4160, 256, 0, stream>>>(pxW2, pxW1, Mm, Rm, W2bf, W1bf, W1Tbf, Mbf, FBT);
  k_xpass_mfma <<<512, 256, 0, stream>>>(x, WXT, vcb, vq0, cneg, h1pre);
  k_langevin <<<512, 512, 0, stream>>>(W1bf, W1Tbf, Mbf, FBT, pxb1, vr0, cneg, dkeys, hfin, capre);
  k_xrecon_mfma <<<4096, 256, 0, stream>>>(hfin, W2bf, pxb2, xre);
  k_tail    <<<2048, 256, 0, stream>>>(h1pre, capre, ln1g, ln1b, ln2g, ln2b, ln3g, ln3b,
                                       fW1, fb1, fW2, fb2, outW, outb, ypred);
}

// Round 7
// 1277.824 us; speedup vs baseline: 1.1632x; 1.1632x over previous
//
#include <hip/hip_runtime.h>
#include <cstdint>
#include <cstddef>
#include <cmath>

#define B_     8192
#define XD_    4096
#define ZD_    1024
#define XE_    64
#define H_     128
#define ZN_    (B_*ZD_)

typedef __attribute__((ext_vector_type(8))) short short8_t;   // 8 x bf16 (4 VGPR)
typedef __attribute__((ext_vector_type(4))) float f32x4_t;    // MFMA accumulator
#define MFMA16(a,b,c) __builtin_amdgcn_mfma_f32_16x16x32_bf16((a),(b),(c),0,0,0)

// ---------------- threefry2x32 (bit-exact vs JAX, partitionable mode — validated R1/R2) ----
__host__ __device__ __forceinline__ uint32_t rotl32_(uint32_t x, int r){ return (x<<r)|(x>>(32-r)); }

__host__ __device__ __forceinline__ void tf2x32(uint32_t k0, uint32_t k1,
                                                uint32_t x0, uint32_t x1,
                                                uint32_t* o0, uint32_t* o1){
  uint32_t k2 = k0 ^ k1 ^ 0x1BD11BDAu;
  x0 += k0; x1 += k1;
  x0 += x1; x1 = rotl32_(x1,13); x1 ^= x0;
  x0 += x1; x1 = rotl32_(x1,15); x1 ^= x0;
  x0 += x1; x1 = rotl32_(x1,26); x1 ^= x0;
  x0 += x1; x1 = rotl32_(x1, 6); x1 ^= x0;
  x0 += k1; x1 += k2 + 1u;
  x0 += x1; x1 = rotl32_(x1,17); x1 ^= x0;
  x0 += x1; x1 = rotl32_(x1,29); x1 ^= x0;
  x0 += x1; x1 = rotl32_(x1,16); x1 ^= x0;
  x0 += x1; x1 = rotl32_(x1,24); x1 ^= x0;
  x0 += k2; x1 += k0 + 2u;
  x0 += x1; x1 = rotl32_(x1,13); x1 ^= x0;
  x0 += x1; x1 = rotl32_(x1,15); x1 ^= x0;
  x0 += x1; x1 = rotl32_(x1,26); x1 ^= x0;
  x0 += x1; x1 = rotl32_(x1, 6); x1 ^= x0;
  x0 += k0; x1 += k1 + 3u;
  x0 += x1; x1 = rotl32_(x1,17); x1 ^= x0;
  x0 += x1; x1 = rotl32_(x1,29); x1 ^= x0;
  x0 += x1; x1 = rotl32_(x1,16); x1 ^= x0;
  x0 += x1; x1 = rotl32_(x1,24); x1 ^= x0;
  x0 += k1; x1 += k2 + 4u;
  x0 += x1; x1 = rotl32_(x1,13); x1 ^= x0;
  x0 += x1; x1 = rotl32_(x1,15); x1 ^= x0;
  x0 += x1; x1 = rotl32_(x1,26); x1 ^= x0;
  x0 += x1; x1 = rotl32_(x1, 6); x1 ^= x0;
  x0 += k2; x1 += k0 + 5u;
  *o0 = x0; *o1 = x1;
}

__device__ __forceinline__ float erfinv_(float x){
  float w = -log1pf(-x*x);
  float p;
  if (w < 5.0f){
    w -= 2.5f;
    p = 2.81022636e-08f;
    p = fmaf(p, w, 3.43273939e-07f);
    p = fmaf(p, w, -3.5233877e-06f);
    p = fmaf(p, w, -4.39150654e-06f);
    p = fmaf(p, w, 0.00021858087f);
    p = fmaf(p, w, -0.00125372503f);
    p = fmaf(p, w, -0.00417768164f);
    p = fmaf(p, w, 0.246640727f);
    p = fmaf(p, w, 1.50140941f);
  } else {
    w = sqrtf(w) - 3.0f;
    p = -0.000200214257f;
    p = fmaf(p, w, 0.000100950558f);
    p = fmaf(p, w, 0.00134934322f);
    p = fmaf(p, w, -0.00367342844f);
    p = fmaf(p, w, 0.00573950773f);
    p = fmaf(p, w, -0.0076224613f);
    p = fmaf(p, w, 0.00943887047f);
    p = fmaf(p, w, 1.00167406f);
    p = fmaf(p, w, 2.83297682f);
  }
  return p * x;
}

__device__ __forceinline__ float bits_to_normal(uint32_t bits){
  float f = __uint_as_float((bits >> 9) | 0x3f800000u) - 1.0f;
  float u = fmaxf(-0.99999994f, fmaf(f, 2.0f, -0.99999994f));
  return 1.41421356f * erfinv_(u);
}

__device__ __forceinline__ float rng_normal(uint32_t k0, uint32_t k1, uint32_t idx){
  uint32_t o0, o1; tf2x32(k0, k1, 0u, idx, &o0, &o1);
  return bits_to_normal(o0 ^ o1);
}

__device__ __forceinline__ ushort f2bf(float f){
  uint32_t u = __float_as_uint(f);
  return (ushort)((u + 0x7FFFu + ((u >> 16) & 1u)) >> 16);
}
__device__ __forceinline__ float bf2f(ushort u){ return __uint_as_float(((uint32_t)u) << 16); }

__device__ __forceinline__ short8_t pack8(float4 a, float4 b){
  short8_t r;
  r[0]=(short)f2bf(a.x); r[1]=(short)f2bf(a.y); r[2]=(short)f2bf(a.z); r[3]=(short)f2bf(a.w);
  r[4]=(short)f2bf(b.x); r[5]=(short)f2bf(b.y); r[6]=(short)f2bf(b.z); r[7]=(short)f2bf(b.w);
  return r;
}

// ---------------- weight-prep kernels (f32) ----------------
__global__ void k_prepA(const float* __restrict__ saWo, const float* __restrict__ saWqkv,
                        const float* __restrict__ caWo, const float* __restrict__ caWqkv,
                        float* __restrict__ S, float* __restrict__ U){
  int blk = blockIdx.x, tid = threadIdx.x;
  int idx = (blk & 255) * 64 + tid;
  int i = idx >> 7, j = idx & 127;
  if (blk < 256){
    float acc = (i == j) ? 1.0f : 0.0f;
    for (int k = 0; k < H_; ++k) acc += saWo[i*H_ + k] * saWqkv[(2*H_ + k)*H_ + j];
    S[idx] = acc;
  } else {
    float acc = 0.0f;
    for (int k = 0; k < H_; ++k) acc += caWo[i*H_ + k] * caWqkv[(2*H_ + k)*H_ + j];
    U[idx] = acc;
  }
}

__global__ void k_prepB(const float* __restrict__ saWo, const float* __restrict__ sabqkv, const float* __restrict__ sabo,
                        const float* __restrict__ caWo, const float* __restrict__ cabqkv, const float* __restrict__ cabo,
                        const float* __restrict__ W2, const float* __restrict__ pb2,
                        float* __restrict__ s0, float* __restrict__ u0, float* __restrict__ cb,
                        uint32_t* __restrict__ dkeys){
  int blk = blockIdx.x, tid = threadIdx.x;
  if (blk == 0 && tid == 0){
    for (uint32_t i = 0; i < 11; ++i){
      uint32_t a, b; tf2x32(0u, 42u, 0u, i, &a, &b);
      dkeys[2*i] = a; dkeys[2*i+1] = b;
    }
  }
  if (blk < 2){
    int i = blk*64 + tid;
    float acc = sabo[i];
    for (int k = 0; k < H_; ++k) acc += saWo[i*H_ + k] * sabqkv[2*H_ + k];
    s0[i] = acc;
  } else if (blk < 4){
    int i = (blk-2)*64 + tid;
    float acc = cabo[i];
    for (int k = 0; k < H_; ++k) acc += caWo[i*H_ + k] * cabqkv[2*H_ + k];
    u0[i] = acc;
  } else {
    int j = (blk-4)*64 + tid;
    float acc = 0.0f;
    for (int c = 0; c < XD_; ++c) acc += pb2[c] * W2[(size_t)c*H_ + j];
    cb[j] = acc;
  }
}

__global__ void k_prepM(const float* __restrict__ W2, float* __restrict__ M){
  int idx = blockIdx.x*64 + threadIdx.x;  // 16384
  int j1 = idx >> 7, j2 = idx & 127;
  float acc = 0.0f;
  for (int c = 0; c < XD_; ++c) acc += W2[(size_t)c*H_ + j1] * W2[(size_t)c*H_ + j2];
  M[idx] = acc;
}

__global__ void k_prepTR(const float* __restrict__ S, const float* __restrict__ U,
                         const float* __restrict__ xpW, const float* __restrict__ zpW,
                         const float* __restrict__ xpb, const float* __restrict__ zpb,
                         const float* __restrict__ s0, const float* __restrict__ u0,
                         float* __restrict__ T, float* __restrict__ R,
                         float* __restrict__ t0, float* __restrict__ r0v){
  int blk = blockIdx.x, tid = threadIdx.x;
  if (blk < 128){
    int idx = blk*64 + tid;
    int i = idx >> 6, e = idx & 63;
    float acc = 0.0f;
    for (int m = 0; m < H_; ++m) acc += S[i*H_ + m] * xpW[m*XE_ + e];
    T[idx] = acc;
  } else if (blk < 2176){
    int idx = (blk-128)*64 + tid;
    int i = idx >> 10, k = idx & 1023;
    float acc = 0.0f;
    for (int m = 0; m < H_; ++m) acc += U[i*H_ + m] * zpW[(size_t)m*ZD_ + k];
    R[idx] = acc;
  } else if (blk < 2178){
    int i = (blk-2176)*64 + tid;
    float acc = s0[i];
    for (int m = 0; m < H_; ++m) acc += S[i*H_ + m] * xpb[m];
    t0[i] = acc;
  } else {
    int i = (blk-2178)*64 + tid;
    float acc = u0[i];
    for (int m = 0; m < H_; ++m) acc += U[i*H_ + m] * zpb[m];
    r0v[i] = acc;
  }
}

__global__ void k_prepWXT(const float* __restrict__ W2, const float* __restrict__ T,
                          const float* __restrict__ embW, const float* __restrict__ embb,
                          const float* __restrict__ t0,
                          ushort* __restrict__ WXT, float* __restrict__ q0){
  int idx = blockIdx.x*256 + threadIdx.x;   // 1048576
  int j = idx >> 12, c = idx & 4095;
  float v;
  if (j < H_) v = W2[(size_t)c*H_ + j];
  else {
    int i = j - H_;
    float acc = 0.0f;
    for (int e = 0; e < XE_; ++e) acc += T[i*XE_ + e] * embW[(size_t)e*XD_ + c];
    v = acc;
  }
  WXT[idx] = f2bf(v);
  if (idx < H_){
    float acc = t0[idx];
    for (int e = 0; e < XE_; ++e) acc += T[idx*XE_ + e] * embb[e];
    q0[idx] = acc;
  }
}

__global__ void k_conv(const float* __restrict__ W2, const float* __restrict__ W1,
                       const float* __restrict__ Mm, const float* __restrict__ R,
                       ushort* __restrict__ W2bf, ushort* __restrict__ W1bf,
                       ushort* __restrict__ W1Tbf, ushort* __restrict__ Mbf,
                       ushort* __restrict__ FBT){
  int idx = blockIdx.x*256 + threadIdx.x;   // 1064960
  if (idx < 524288) W2bf[idx] = f2bf(W2[idx]);
  else if (idx < 655360){ int i = idx - 524288; W1bf[i] = f2bf(W1[i]); }
  else if (idx < 786432){ int i = idx - 655360; int k = i >> 7, h = i & 127;
    W1Tbf[i] = f2bf(W1[h*ZD_ + k]); }
  else if (idx < 802816){ int i = idx - 786432; Mbf[i] = f2bf(Mm[i]); }
  else { int i = idx - 802816; int j = i >> 10, k = i & 1023;
    FBT[i] = f2bf(j < H_ ? W1[j*ZD_ + k] : R[(size_t)(j-H_)*ZD_ + k]); }
}

// ---------------- x-pass (MFMA, dbuf, 1 barrier/iter): [cneg | h1pre] = x @ WXT^T ----
// BM=32, BN=128, grid 512, 256 thr.
__global__ __launch_bounds__(256) void k_xpass_mfma(
    const float* __restrict__ x, const ushort* __restrict__ WXT,
    const float* __restrict__ cb, const float* __restrict__ q0,
    float* __restrict__ cneg, float* __restrict__ h1pre){
  __shared__ __align__(16) ushort xt[2][32*72];
  __shared__ __align__(16) ushort bt[2][128*72];
  const int t = threadIdx.x, lane = t & 63, w = t >> 6;
  const int bm = blockIdx.x >> 1, bn = blockIdx.x & 1;
  const int row0 = bm*32, ncol0 = bn*128;
  const int l15 = lane & 15, kq8 = (lane >> 4)*8, rq = (lane >> 4)*4;
  const int rt = w & 1, cb4 = (w >> 1)*4;
  const int xr = t >> 3, xk = (t & 7)*8;
  const int wn = t >> 1, wk = (t & 1)*32;
  f32x4_t acc[4] = {};
  // prologue: stage tile 0
  {
    float4 v0 = *(const float4*)&x[(size_t)(row0+xr)*XD_ + xk];
    float4 v1 = *(const float4*)&x[(size_t)(row0+xr)*XD_ + xk + 4];
    union { ushort u[8]; uint4 q; } p;
    p.u[0]=f2bf(v0.x); p.u[1]=f2bf(v0.y); p.u[2]=f2bf(v0.z); p.u[3]=f2bf(v0.w);
    p.u[4]=f2bf(v1.x); p.u[5]=f2bf(v1.y); p.u[6]=f2bf(v1.z); p.u[7]=f2bf(v1.w);
    *(uint4*)&xt[0][xr*72 + xk] = p.q;
    const ushort* s = &WXT[(size_t)(ncol0+wn)*XD_ + wk];
    uint4 b0v=*(const uint4*)s, b1v=*(const uint4*)(s+8), b2v=*(const uint4*)(s+16), b3v=*(const uint4*)(s+24);
    ushort* d = &bt[0][wn*72 + wk];
    *(uint4*)d=b0v; *(uint4*)(d+8)=b1v; *(uint4*)(d+16)=b2v; *(uint4*)(d+24)=b3v;
  }
  for (int it = 0; it < 64; ++it){
    const int cur = it & 1;
    float4 v0, v1; uint4 b0v, b1v, b2v, b3v;
    if (it < 63){
      const int kt = (it+1)*64;
      v0 = *(const float4*)&x[(size_t)(row0+xr)*XD_ + kt + xk];
      v1 = *(const float4*)&x[(size_t)(row0+xr)*XD_ + kt + xk + 4];
      const ushort* s = &WXT[(size_t)(ncol0+wn)*XD_ + kt + wk];
      b0v=*(const uint4*)s; b1v=*(const uint4*)(s+8); b2v=*(const uint4*)(s+16); b3v=*(const uint4*)(s+24);
    }
    __syncthreads();
    #pragma unroll
    for (int h = 0; h < 2; ++h){
      short8_t a = *(const short8_t*)&xt[cur][(rt*16+l15)*72 + h*32 + kq8];
      #pragma unroll
      for (int c = 0; c < 4; ++c){
        short8_t b = *(const short8_t*)&bt[cur][((cb4+c)*16+l15)*72 + h*32 + kq8];
        acc[c] = MFMA16(a, b, acc[c]);
      }
    }
    if (it < 63){
      const int nxt = cur ^ 1;
      union { ushort u[8]; uint4 q; } p;
      p.u[0]=f2bf(v0.x); p.u[1]=f2bf(v0.y); p.u[2]=f2bf(v0.z); p.u[3]=f2bf(v0.w);
      p.u[4]=f2bf(v1.x); p.u[5]=f2bf(v1.y); p.u[6]=f2bf(v1.z); p.u[7]=f2bf(v1.w);
      *(uint4*)&xt[nxt][xr*72 + xk] = p.q;
      ushort* d = &bt[nxt][wn*72 + wk];
      *(uint4*)d=b0v; *(uint4*)(d+8)=b1v; *(uint4*)(d+16)=b2v; *(uint4*)(d+24)=b3v;
    }
  }
  #pragma unroll
  for (int c = 0; c < 4; ++c){
    int jl = (cb4+c)*16 + l15;
    #pragma unroll
    for (int r = 0; r < 4; ++r){
      int row = row0 + rt*16 + rq + r;
      float v = acc[c][r];
      if (bn == 0) cneg[(size_t)row*H_ + jl] = 2.0f*(cb[jl] - v);
      else         h1pre[(size_t)row*H_ + jl] = v + q0[jl];
    }
  }
}

// ---------------- fused Langevin: init + 10 steps + finalz; z lives in LDS ----------
// grid 512 blocks x 512 thr (8 waves). BM=16 rows/block.
// R3-R6 lesson: the VGPR allocator caps this kernel at 128 regs regardless of
// launch_bounds/waves_per_eu hints; z-in-VGPR (needs ~160) always spilled to
// scratch (~1 GB/launch => kernel was 100% scratch-BW-bound at ~1 TB/s).
// Fix: z master copy in LDS (f32, [16][1028] pad => 2-way bank alias only).
// MFMA A-fragments read z directly from LDS (+cvt); P3 owner-updates z in place
// (f32 delta, no bf16 round-trip, one fewer barrier/tile). ~90 live VGPRs.
__global__ __launch_bounds__(512) void k_langevin(
    const ushort* __restrict__ W1bf, const ushort* __restrict__ W1Tbf,
    const ushort* __restrict__ Mbf, const ushort* __restrict__ FBT,
    const float* __restrict__ b1, const float* __restrict__ r0v,
    const float* __restrict__ cneg, const uint32_t* __restrict__ dkeys,
    ushort* __restrict__ hfin_bf, float* __restrict__ capre){
  __shared__ __align__(16) float  zlds[16][1028];      // 65792 B
  __shared__ __align__(16) ushort ws_[2][128*72];      // 36864 B
  __shared__ __align__(16) ushort abuf[16*136];        //  4352 B
  __shared__ __align__(16) ushort glbuf[16*136];       //  4352 B  (total 111360)

  const int t = threadIdx.x, lane = t & 63, w = t >> 6;
  const int l15 = lane & 15, kq8 = (lane >> 4)*8, rq = (lane >> 4)*4;
  const int b0 = blockIdx.x * 16;
  const int myc = w*16 + l15;

  // ---- z0 init (RNG) into LDS
  {
    const uint32_t k0 = dkeys[0], k1 = dkeys[1];
    const int row16 = t >> 5, c4 = (t & 31)*4;
    #pragma unroll
    for (int i = 0; i < 8; ++i){
      const int col = c4 + 128*i;
      uint32_t base = (uint32_t)(b0 + row16)*1024u + (uint32_t)col;
      float4 v;
      v.x = rng_normal(k0,k1,base+0);
      v.y = rng_normal(k0,k1,base+1);
      v.z = rng_normal(k0,k1,base+2);
      v.w = rng_normal(k0,k1,base+3);
      *(float4*)&zlds[row16][col] = v;
    }
  }
  const float bb = b1[myc];
  float cn[4];
  #pragma unroll
  for (int r = 0; r < 4; ++r) cn[r] = cneg[(size_t)(b0+rq+r)*H_ + myc];

  for (int s = 0; s < 10; ++s){
    const uint32_t nk0 = dkeys[2+2*s], nk1 = dkeys[3+2*s];
    // ---------- P1: h = z @ W1^T  (K=1024, dbuf W1, 1 barrier/iter, z direct from LDS)
    f32x4_t acc = {};
    {
      const ushort* sw = &W1bf[(size_t)(t>>2)*ZD_ + (t&3)*16];
      uint4 a0 = *(const uint4*)sw, a1 = *(const uint4*)(sw+8);
      ushort* d = &ws_[0][(t>>2)*72 + (t&3)*16];
      *(uint4*)d = a0; *(uint4*)(d+8) = a1;
    }
    #pragma unroll
    for (int it = 0; it < 16; ++it){
      const int cur = it & 1;
      uint4 a0, a1;
      if (it < 15){
        const ushort* sw = &W1bf[(size_t)(t>>2)*ZD_ + (it+1)*64 + (t&3)*16];
        a0 = *(const uint4*)sw; a1 = *(const uint4*)(sw+8);
      }
      __syncthreads();
      #pragma unroll
      for (int h = 0; h < 2; ++h){
        const float* zp = &zlds[l15][it*64 + h*32 + kq8];
        short8_t av = pack8(*(const float4*)zp, *(const float4*)(zp+4));
        short8_t bv = *(const short8_t*)&ws_[cur][myc*72 + h*32 + kq8];
        acc = MFMA16(av, bv, acc);
      }
      if (it < 15){
        ushort* d = &ws_[cur^1][(t>>2)*72 + (t&3)*16];
        *(uint4*)d = a0; *(uint4*)(d+8) = a1;
      }
    }
    float hv[4];
    #pragma unroll
    for (int r = 0; r < 4; ++r){
      hv[r] = acc[r] + bb;
      abuf[(rq+r)*136 + myc] = f2bf(hv[r] > 0.f ? hv[r] : 0.f);
    }
    __syncthreads();           // abuf ready; P1 ws reads done
    // ---------- stage M into ws_[0]/ws_[1]
    {
      const int n = t >> 2, kk = (t & 3)*32;
      const ushort* sm = &Mbf[(size_t)n*H_ + kk];
      uint4 m0=*(const uint4*)sm, m1=*(const uint4*)(sm+8), m2=*(const uint4*)(sm+16), m3=*(const uint4*)(sm+24);
      ushort* d = &ws_[kk>>6][n*72 + (kk&63)];
      *(uint4*)d=m0; *(uint4*)(d+8)=m1; *(uint4*)(d+16)=m2; *(uint4*)(d+24)=m3;
    }
    __syncthreads();
    // ---------- P2: g2 = a @ M
    f32x4_t acc2 = {};
    #pragma unroll
    for (int c = 0; c < 2; ++c)
      #pragma unroll
      for (int h = 0; h < 2; ++h){
        short8_t av = *(const short8_t*)&abuf[l15*136 + c*64 + h*32 + kq8];
        short8_t bv = *(const short8_t*)&ws_[c][myc*72 + h*32 + kq8];
        acc2 = MFMA16(av, bv, acc2);
      }
    #pragma unroll
    for (int r = 0; r < 4; ++r){
      float g = (hv[r] > 0.f) ? fmaf(2.f, acc2[r], cn[r]) : 0.f;
      glbuf[(rq+r)*136 + myc] = f2bf(g);
    }
    // ---------- P3: z -= hstep*(g @ W1) + noise ; 8 n-tiles; owner updates z in place
    #pragma unroll
    for (int nt = 0; nt < 8; ++nt){
      const int n = t >> 2, kk = (t & 3)*32;
      const ushort* sw = &W1Tbf[(size_t)(nt*128 + n)*H_ + kk];
      uint4 v0=*(const uint4*)sw, v1=*(const uint4*)(sw+8), v2=*(const uint4*)(sw+16), v3=*(const uint4*)(sw+24);
      __syncthreads();         // prev ws reads done (P2 for nt=0); glbuf visible (nt=0)
      {
        ushort* d = &ws_[kk>>6][n*72 + (kk&63)];
        *(uint4*)d=v0; *(uint4*)(d+8)=v1; *(uint4*)(d+16)=v2; *(uint4*)(d+24)=v3;
      }
      __syncthreads();         // ws ready
      f32x4_t acc3 = {};
      #pragma unroll
      for (int c = 0; c < 2; ++c)
        #pragma unroll
        for (int h = 0; h < 2; ++h){
          short8_t av = *(const short8_t*)&glbuf[l15*136 + c*64 + h*32 + kq8];
          short8_t bv = *(const short8_t*)&ws_[c][myc*72 + h*32 + kq8];
          acc3 = MFMA16(av, bv, acc3);
        }
      const int col = nt*128 + myc;
      #pragma unroll
      for (int r = 0; r < 4; ++r){
        const int row = rq + r;
        uint32_t idx = (uint32_t)(b0+row)*1024u + (uint32_t)col;
        float t2 = fmaf(-0.005f, acc3[r], zlds[row][col]);
        zlds[row][col] = fmaf(0.1f, rng_normal(nk0,nk1,idx), t2);
      }
    }
    __syncthreads();           // z updates visible before next step's P1 reads
  }

  // ---------- finalz: [hfin | capre] = z @ FBT^T  (K=1024, N=256)
  f32x4_t fac0 = {}, fac1 = {};
  #pragma unroll
  for (int it = 0; it < 16; ++it){
    const int n2 = t >> 1, kh = (t & 1)*32;
    const ushort* sf = &FBT[(size_t)n2*ZD_ + it*64 + kh];
    uint4 f0=*(const uint4*)sf, f1=*(const uint4*)(sf+8), f2v=*(const uint4*)(sf+16), f3=*(const uint4*)(sf+24);
    __syncthreads();           // prev iter MFMA reads done
    {
      ushort* d = (n2 < 128) ? &ws_[0][n2*72 + kh] : &ws_[1][(n2-128)*72 + kh];
      *(uint4*)d=f0; *(uint4*)(d+8)=f1; *(uint4*)(d+16)=f2v; *(uint4*)(d+24)=f3;
    }
    __syncthreads();
    #pragma unroll
    for (int h = 0; h < 2; ++h){
      const float* zp = &zlds[l15][it*64 + h*32 + kq8];
      short8_t av = pack8(*(const float4*)zp, *(const float4*)(zp+4));
      short8_t bv0 = *(const short8_t*)&ws_[0][myc*72 + h*32 + kq8];
      fac0 = MFMA16(av, bv0, fac0);
      short8_t bv1 = *(const short8_t*)&ws_[1][myc*72 + h*32 + kq8];
      fac1 = MFMA16(av, bv1, fac1);
    }
  }
  {
    const float rv = r0v[myc];
    #pragma unroll
    for (int r = 0; r < 4; ++r){
      int row = b0 + rq + r;
      float h0 = fac0[r] + bb;
      hfin_bf[(size_t)row*H_ + myc] = f2bf(h0 > 0.f ? h0 : 0.f);
      capre[(size_t)row*H_ + myc] = fac1[r] + rv;
    }
  }
}

// ---------------- x_recon (MFMA): out = hfin @ W2^T + b2 ----------------
__global__ __launch_bounds__(256) void k_xrecon_mfma(
    const ushort* __restrict__ hfin_bf, const ushort* __restrict__ W2bf,
    const float* __restrict__ b2, float* __restrict__ out){
  __shared__ __align__(16) ushort at[64*136];
  __shared__ __align__(16) ushort bt[128*136];
  const int tid = threadIdx.x, lane = tid & 63, w = tid >> 6;
  const int bm = blockIdx.x >> 5, bn = blockIdx.x & 31;
  const int row0 = bm*64, c0 = bn*128;
  const int l15 = lane & 15, kq8 = (lane >> 4)*8, rq = (lane >> 4)*4;
  { int r = tid >> 2, kq = (tid & 3)*32;
    const ushort* src = &hfin_bf[(size_t)(row0 + r)*H_ + kq];
    #pragma unroll
    for (int i = 0; i < 4; ++i) *(uint4*)&at[r*136 + kq + 8*i] = *(const uint4*)(src + 8*i);
  }
  { int n = tid >> 1, kh = (tid & 1)*64;
    const ushort* src = &W2bf[(size_t)(c0 + n)*H_ + kh];
    #pragma unroll
    for (int i = 0; i < 8; ++i) *(uint4*)&bt[n*136 + kh + 8*i] = *(const uint4*)(src + 8*i);
  }
  __syncthreads();
  f32x4_t acc[8] = {};
  #pragma unroll
  for (int k = 0; k < 4; ++k){
    short8_t a = *(const short8_t*)&at[(w*16 + l15)*136 + k*32 + kq8];
    #pragma unroll
    for (int nf = 0; nf < 8; ++nf){
      short8_t b = *(const short8_t*)&bt[(nf*16 + l15)*136 + k*32 + kq8];
      acc[nf] = MFMA16(a, b, acc[nf]);
    }
  }
  #pragma unroll
  for (int nf = 0; nf < 8; ++nf){
    int c = c0 + nf*16 + l15;
    float bbv = b2[c];
    #pragma unroll
    for (int r = 0; r < 4; ++r){
      int row = row0 + w*16 + rq + r;
      out[(size_t)row*XD_ + c] = acc[nf][r] + bbv;
    }
  }
}

// ---------------- per-row transformer tail -> y_pred ----------------
__device__ __forceinline__ float wsum64(float v){
  #pragma unroll
  for (int off = 32; off > 0; off >>= 1) v += __shfl_xor(v, off, 64);
  return v;
}

__global__ __launch_bounds__(256) void k_tail(
    const float* __restrict__ h1pre, const float* __restrict__ capre,
    const float* __restrict__ ln1g, const float* __restrict__ ln1b,
    const float* __restrict__ ln2g, const float* __restrict__ ln2b,
    const float* __restrict__ ln3g, const float* __restrict__ ln3b,
    const float* __restrict__ fW1, const float* __restrict__ fb1,
    const float* __restrict__ fW2, const float* __restrict__ fb2,
    const float* __restrict__ outW, const float* __restrict__ outb,
    float* __restrict__ y){
  __shared__ float sh2[4][128];
  __shared__ float st1[4][128];
  const int tid = threadIdx.x;
  const int w = tid >> 6;
  const int l = tid & 63;
  const int b = blockIdx.x * 4 + w;
  const float* hp = h1pre + (size_t)b * H_;
  const float* cp = capre + (size_t)b * H_;
  float x0 = hp[l], x1 = hp[l+64];
  float m = wsum64(x0 + x1) * (1.0f/128.0f);
  float d0 = x0 - m, d1 = x1 - m;
  float v = wsum64(d0*d0 + d1*d1) * (1.0f/128.0f);
  float rs = rsqrtf(v + 1e-5f);
  float h1a = d0 * rs * ln1g[l]    + ln1b[l];
  float h1b = d1 * rs * ln1g[l+64] + ln1b[l+64];
  x0 = h1a + cp[l]; x1 = h1b + cp[l+64];
  m = wsum64(x0 + x1) * (1.0f/128.0f);
  d0 = x0 - m; d1 = x1 - m;
  v = wsum64(d0*d0 + d1*d1) * (1.0f/128.0f);
  rs = rsqrtf(v + 1e-5f);
  float h2a = d0 * rs * ln2g[l]    + ln2b[l];
  float h2b = d1 * rs * ln2g[l+64] + ln2b[l+64];
  sh2[w][l] = h2a; sh2[w][l+64] = h2b;
  __syncthreads();
  float ta = fb1[l], tb = fb1[l+64];
  #pragma unroll 8
  for (int m4 = 0; m4 < H_; m4 += 4){
    float4 hv = *(const float4*)&sh2[w][m4];
    float4 wa = *(const float4*)&fW1[(size_t)l*H_ + m4];
    float4 wb = *(const float4*)&fW1[(size_t)(l+64)*H_ + m4];
    ta = fmaf(wa.x, hv.x, ta); ta = fmaf(wa.y, hv.y, ta); ta = fmaf(wa.z, hv.z, ta); ta = fmaf(wa.w, hv.w, ta);
    tb = fmaf(wb.x, hv.x, tb); tb = fmaf(wb.y, hv.y, tb); tb = fmaf(wb.z, hv.z, tb); tb = fmaf(wb.w, hv.w, tb);
  }
  ta = fmaxf(ta, 0.0f); tb = fmaxf(tb, 0.0f);
  st1[w][l] = ta; st1[w][l+64] = tb;
  __syncthreads();
  float fa = fb2[l], fbv = fb2[l+64];
  #pragma unroll 8
  for (int m4 = 0; m4 < H_; m4 += 4){
    float4 tv = *(const float4*)&st1[w][m4];
    float4 wa = *(const float4*)&fW2[(size_t)l*H_ + m4];
    float4 wb = *(const float4*)&fW2[(size_t)(l+64)*H_ + m4];
    fa  = fmaf(wa.x, tv.x, fa);  fa  = fmaf(wa.y, tv.y, fa);  fa  = fmaf(wa.z, tv.z, fa);  fa  = fmaf(wa.w, tv.w, fa);
    fbv = fmaf(wb.x, tv.x, fbv); fbv = fmaf(wb.y, tv.y, fbv); fbv = fmaf(wb.z, tv.z, fbv); fbv = fmaf(wb.w, tv.w, fbv);
  }
  x0 = h2a + fa; x1 = h2b + fbv;
  m = wsum64(x0 + x1) * (1.0f/128.0f);
  d0 = x0 - m; d1 = x1 - m;
  v = wsum64(d0*d0 + d1*d1) * (1.0f/128.0f);
  rs = rsqrtf(v + 1e-5f);
  float h3a = d0 * rs * ln3g[l]    + ln3b[l];
  float h3b = d1 * rs * ln3g[l+64] + ln3b[l+64];
  float py = wsum64(outW[l]*h3a + outW[l+64]*h3b);
  if (l == 0) y[b] = py + outb[0];
}

// ---------------- host ----------------
extern "C" void kernel_launch(void* const* d_in, const int* in_sizes, int n_in,
                              void* d_out, int out_size, void* d_ws, size_t ws_size,
                              hipStream_t stream){
  const float* x      = (const float*)d_in[0];
  const float* pxW1   = (const float*)d_in[1];
  const float* pxb1   = (const float*)d_in[2];
  const float* pxW2   = (const float*)d_in[3];
  const float* pxb2   = (const float*)d_in[4];
  const float* embW   = (const float*)d_in[5];
  const float* embb   = (const float*)d_in[6];
  const float* xpW    = (const float*)d_in[7];
  const float* xpb    = (const float*)d_in[8];
  const float* zpW    = (const float*)d_in[9];
  const float* zpb    = (const float*)d_in[10];
  const float* saWqkv = (const float*)d_in[11];
  const float* sabqkv = (const float*)d_in[12];
  const float* saWo   = (const float*)d_in[13];
  const float* sabo   = (const float*)d_in[14];
  const float* caWqkv = (const float*)d_in[15];
  const float* cabqkv = (const float*)d_in[16];
  const float* caWo   = (const float*)d_in[17];
  const float* cabo   = (const float*)d_in[18];
  const float* fW1    = (const float*)d_in[19];
  const float* fb1    = (const float*)d_in[20];
  const float* fW2    = (const float*)d_in[21];
  const float* fb2    = (const float*)d_in[22];
  const float* ln1g   = (const float*)d_in[23];
  const float* ln1b   = (const float*)d_in[24];
  const float* ln2g   = (const float*)d_in[25];
  const float* ln2b   = (const float*)d_in[26];
  const float* ln3g   = (const float*)d_in[27];
  const float* ln3b   = (const float*)d_in[28];
  const float* outW   = (const float*)d_in[29];
  const float* outb   = (const float*)d_in[30];
  (void)in_sizes; (void)n_in; (void)out_size; (void)ws_size;

  float* ws    = (float*)d_ws;
  float* cneg  = ws;                          // 1048576
  float* h1pre = cneg + (size_t)B_*H_;        // 1048576
  float* capre = h1pre + (size_t)B_*H_;       // 1048576
  float* Rm    = capre + (size_t)B_*H_;       // 131072
  float* Mm    = Rm + (size_t)H_*ZD_;         // 16384
  float* Sm    = Mm + H_*H_;                  // 16384
  float* Um    = Sm + H_*H_;                  // 16384
  float* Tm    = Um + H_*H_;                  // 8192
  float* vs0   = Tm + H_*XE_;
  float* vu0   = vs0 + H_;
  float* vt0   = vu0 + H_;
  float* vq0   = vt0 + H_;
  float* vr0   = vq0 + H_;
  float* vcb   = vr0 + H_;
  uint32_t* dkeys = (uint32_t*)(vcb + H_);    // 32 u32
  ushort* WXT   = (ushort*)(dkeys + 32);      // 1048576
  ushort* W2bf  = WXT + (size_t)256*XD_;      // 524288
  ushort* W1bf  = W2bf + (size_t)XD_*H_;      // 131072
  ushort* W1Tbf = W1bf + (size_t)H_*ZD_;      // 131072
  ushort* Mbf   = W1Tbf + (size_t)ZD_*H_;     // 16384
  ushort* FBT   = Mbf + H_*H_;                // 262144
  ushort* hfin  = FBT + (size_t)256*ZD_;      // 1048576

  float* xre   = (float*)d_out;
  float* ypred = xre + (size_t)B_*XD_;

  k_prepA   <<<512,  64, 0, stream>>>(saWo, saWqkv, caWo, caWqkv, Sm, Um);
  k_prepB   <<<6,    64, 0, stream>>>(saWo, sabqkv, sabo, caWo, cabqkv, cabo, pxW2, pxb2,
                                      vs0, vu0, vcb, dkeys);
  k_prepM   <<<256,  64, 0, stream>>>(pxW2, Mm);
  k_prepTR  <<<2180, 64, 0, stream>>>(Sm, Um, xpW, zpW, xpb, zpb, vs0, vu0, Tm, Rm, vt0, vr0);
  k_prepWXT <<<4096, 256, 0, stream>>>(pxW2, Tm, embW, embb, vt0, WXT, vq0);
  k_conv    <<<4160, 256, 0, stream>>>(pxW2, pxW1, Mm, Rm, W2bf, W1bf, W1Tbf, Mbf, FBT);
  k_xpass_mfma <<<512, 256, 0, stream>>>(x, WXT, vcb, vq0, cneg, h1pre);
  k_langevin <<<512, 512, 0, stream>>>(W1bf, W1Tbf, Mbf, FBT, pxb1, vr0, cneg, dkeys, hfin, capre);
  k_xrecon_mfma <<<4096, 256, 0, stream>>>(hfin, W2bf, pxb2, xre);
  k_tail    <<<2048, 256, 0, stream>>>(h1pre, capre, ln1g, ln1b, ln2g, ln2b, ln3g, ln3b,
                                       fW1, fb1, fW2, fb2, outW, outb, ypred);
}

// Round 8
// 919.811 us; speedup vs baseline: 1.6159x; 1.3892x over previous
//
#include <hip/hip_runtime.h>
#include <hip/hip_bf16.h>
#include <cstdint>
#include <cstddef>
#include <cmath>

#define B_     8192
#define XD_    4096
#define ZD_    1024
#define XE_    64
#define H_     128
#define ZN_    (B_*ZD_)

typedef __attribute__((ext_vector_type(8))) short short8_t;   // 8 x bf16 (4 VGPR)
typedef __attribute__((ext_vector_type(4))) float f32x4_t;    // MFMA accumulator
#define MFMA16(a,b,c) __builtin_amdgcn_mfma_f32_16x16x32_bf16((a),(b),(c),0,0,0)

// ---------------- threefry2x32 (bit-exact vs JAX, partitionable mode — validated R1/R2) ----
__host__ __device__ __forceinline__ uint32_t rotl32_(uint32_t x, int r){ return (x<<r)|(x>>(32-r)); }

__host__ __device__ __forceinline__ void tf2x32(uint32_t k0, uint32_t k1,
                                                uint32_t x0, uint32_t x1,
                                                uint32_t* o0, uint32_t* o1){
  uint32_t k2 = k0 ^ k1 ^ 0x1BD11BDAu;
  x0 += k0; x1 += k1;
  x0 += x1; x1 = rotl32_(x1,13); x1 ^= x0;
  x0 += x1; x1 = rotl32_(x1,15); x1 ^= x0;
  x0 += x1; x1 = rotl32_(x1,26); x1 ^= x0;
  x0 += x1; x1 = rotl32_(x1, 6); x1 ^= x0;
  x0 += k1; x1 += k2 + 1u;
  x0 += x1; x1 = rotl32_(x1,17); x1 ^= x0;
  x0 += x1; x1 = rotl32_(x1,29); x1 ^= x0;
  x0 += x1; x1 = rotl32_(x1,16); x1 ^= x0;
  x0 += x1; x1 = rotl32_(x1,24); x1 ^= x0;
  x0 += k2; x1 += k0 + 2u;
  x0 += x1; x1 = rotl32_(x1,13); x1 ^= x0;
  x0 += x1; x1 = rotl32_(x1,15); x1 ^= x0;
  x0 += x1; x1 = rotl32_(x1,26); x1 ^= x0;
  x0 += x1; x1 = rotl32_(x1, 6); x1 ^= x0;
  x0 += k0; x1 += k1 + 3u;
  x0 += x1; x1 = rotl32_(x1,17); x1 ^= x0;
  x0 += x1; x1 = rotl32_(x1,29); x1 ^= x0;
  x0 += x1; x1 = rotl32_(x1,16); x1 ^= x0;
  x0 += x1; x1 = rotl32_(x1,24); x1 ^= x0;
  x0 += k1; x1 += k2 + 4u;
  x0 += x1; x1 = rotl32_(x1,13); x1 ^= x0;
  x0 += x1; x1 = rotl32_(x1,15); x1 ^= x0;
  x0 += x1; x1 = rotl32_(x1,26); x1 ^= x0;
  x0 += x1; x1 = rotl32_(x1, 6); x1 ^= x0;
  x0 += k2; x1 += k0 + 5u;
  *o0 = x0; *o1 = x1;
}

// XLA ErfInv32; w via fast v_log (accuracy ~1e-6 on noise — tolerance-covered;
// threefry BITS stay bit-exact). fmaf(-x,x,1) = exact 1-x^2 to one rounding.
__device__ __forceinline__ float erfinv_(float x){
  float w = -__logf(fmaf(-x, x, 1.0f));
  float p;
  if (w < 5.0f){
    w -= 2.5f;
    p = 2.81022636e-08f;
    p = fmaf(p, w, 3.43273939e-07f);
    p = fmaf(p, w, -3.5233877e-06f);
    p = fmaf(p, w, -4.39150654e-06f);
    p = fmaf(p, w, 0.00021858087f);
    p = fmaf(p, w, -0.00125372503f);
    p = fmaf(p, w, -0.00417768164f);
    p = fmaf(p, w, 0.246640727f);
    p = fmaf(p, w, 1.50140941f);
  } else {
    w = sqrtf(w) - 3.0f;
    p = -0.000200214257f;
    p = fmaf(p, w, 0.000100950558f);
    p = fmaf(p, w, 0.00134934322f);
    p = fmaf(p, w, -0.00367342844f);
    p = fmaf(p, w, 0.00573950773f);
    p = fmaf(p, w, -0.0076224613f);
    p = fmaf(p, w, 0.00943887047f);
    p = fmaf(p, w, 1.00167406f);
    p = fmaf(p, w, 2.83297682f);
  }
  return p * x;
}

__device__ __forceinline__ float bits_to_normal(uint32_t bits){
  float f = __uint_as_float((bits >> 9) | 0x3f800000u) - 1.0f;
  float u = fmaxf(-0.99999994f, fmaf(f, 2.0f, -0.99999994f));
  return 1.41421356f * erfinv_(u);
}

__device__ __forceinline__ float rng_normal(uint32_t k0, uint32_t k1, uint32_t idx){
  uint32_t o0, o1; tf2x32(k0, k1, 0u, idx, &o0, &o1);
  return bits_to_normal(o0 ^ o1);
}

// native RNE f32->bf16 (compiler emits HW cvt; m240: don't hand-write)
__device__ __forceinline__ ushort f2bf(float f){
  return __builtin_bit_cast(ushort, __float2bfloat16(f));
}

// ---------------- weight-prep kernels (f32) ----------------
__global__ void k_prepA(const float* __restrict__ saWo, const float* __restrict__ saWqkv,
                        const float* __restrict__ caWo, const float* __restrict__ caWqkv,
                        float* __restrict__ S, float* __restrict__ U){
  int blk = blockIdx.x, tid = threadIdx.x;
  int idx = (blk & 255) * 64 + tid;
  int i = idx >> 7, j = idx & 127;
  if (blk < 256){
    float acc = (i == j) ? 1.0f : 0.0f;
    for (int k = 0; k < H_; ++k) acc += saWo[i*H_ + k] * saWqkv[(2*H_ + k)*H_ + j];
    S[idx] = acc;
  } else {
    float acc = 0.0f;
    for (int k = 0; k < H_; ++k) acc += caWo[i*H_ + k] * caWqkv[(2*H_ + k)*H_ + j];
    U[idx] = acc;
  }
}

__global__ void k_prepB(const float* __restrict__ saWo, const float* __restrict__ sabqkv, const float* __restrict__ sabo,
                        const float* __restrict__ caWo, const float* __restrict__ cabqkv, const float* __restrict__ cabo,
                        const float* __restrict__ W2, const float* __restrict__ pb2,
                        float* __restrict__ s0, float* __restrict__ u0, float* __restrict__ cb,
                        uint32_t* __restrict__ dkeys){
  int blk = blockIdx.x, tid = threadIdx.x;
  if (blk == 0 && tid == 0){
    for (uint32_t i = 0; i < 11; ++i){
      uint32_t a, b; tf2x32(0u, 42u, 0u, i, &a, &b);
      dkeys[2*i] = a; dkeys[2*i+1] = b;
    }
  }
  if (blk < 2){
    int i = blk*64 + tid;
    float acc = sabo[i];
    for (int k = 0; k < H_; ++k) acc += saWo[i*H_ + k] * sabqkv[2*H_ + k];
    s0[i] = acc;
  } else if (blk < 4){
    int i = (blk-2)*64 + tid;
    float acc = cabo[i];
    for (int k = 0; k < H_; ++k) acc += caWo[i*H_ + k] * cabqkv[2*H_ + k];
    u0[i] = acc;
  } else {
    int j = (blk-4)*64 + tid;
    float acc = 0.0f;
    for (int c = 0; c < XD_; ++c) acc += pb2[c] * W2[(size_t)c*H_ + j];
    cb[j] = acc;
  }
}

__global__ void k_prepM(const float* __restrict__ W2, float* __restrict__ M){
  int idx = blockIdx.x*64 + threadIdx.x;  // 16384
  int j1 = idx >> 7, j2 = idx & 127;
  float acc = 0.0f;
  for (int c = 0; c < XD_; ++c) acc += W2[(size_t)c*H_ + j1] * W2[(size_t)c*H_ + j2];
  M[idx] = acc;
}

__global__ void k_prepTR(const float* __restrict__ S, const float* __restrict__ U,
                         const float* __restrict__ xpW, const float* __restrict__ zpW,
                         const float* __restrict__ xpb, const float* __restrict__ zpb,
                         const float* __restrict__ s0, const float* __restrict__ u0,
                         float* __restrict__ T, float* __restrict__ R,
                         float* __restrict__ t0, float* __restrict__ r0v){
  int blk = blockIdx.x, tid = threadIdx.x;
  if (blk < 128){
    int idx = blk*64 + tid;
    int i = idx >> 6, e = idx & 63;
    float acc = 0.0f;
    for (int m = 0; m < H_; ++m) acc += S[i*H_ + m] * xpW[m*XE_ + e];
    T[idx] = acc;
  } else if (blk < 2176){
    int idx = (blk-128)*64 + tid;
    int i = idx >> 10, k = idx & 1023;
    float acc = 0.0f;
    for (int m = 0; m < H_; ++m) acc += U[i*H_ + m] * zpW[(size_t)m*ZD_ + k];
    R[idx] = acc;
  } else if (blk < 2178){
    int i = (blk-2176)*64 + tid;
    float acc = s0[i];
    for (int m = 0; m < H_; ++m) acc += S[i*H_ + m] * xpb[m];
    t0[i] = acc;
  } else {
    int i = (blk-2178)*64 + tid;
    float acc = u0[i];
    for (int m = 0; m < H_; ++m) acc += U[i*H_ + m] * zpb[m];
    r0v[i] = acc;
  }
}

__global__ void k_prepWXT(const float* __restrict__ W2, const float* __restrict__ T,
                          const float* __restrict__ embW, const float* __restrict__ embb,
                          const float* __restrict__ t0,
                          ushort* __restrict__ WXT, float* __restrict__ q0){
  int idx = blockIdx.x*256 + threadIdx.x;   // 1048576
  int j = idx >> 12, c = idx & 4095;
  float v;
  if (j < H_) v = W2[(size_t)c*H_ + j];
  else {
    int i = j - H_;
    float acc = 0.0f;
    for (int e = 0; e < XE_; ++e) acc += T[i*XE_ + e] * embW[(size_t)e*XD_ + c];
    v = acc;
  }
  WXT[idx] = f2bf(v);
  if (idx < H_){
    float acc = t0[idx];
    for (int e = 0; e < XE_; ++e) acc += T[idx*XE_ + e] * embb[e];
    q0[idx] = acc;
  }
}

__global__ void k_conv(const float* __restrict__ W2, const float* __restrict__ W1,
                       const float* __restrict__ Mm, const float* __restrict__ R,
                       ushort* __restrict__ W2bf, ushort* __restrict__ W1bf,
                       ushort* __restrict__ W1Tbf, ushort* __restrict__ Mbf,
                       ushort* __restrict__ FBT){
  int idx = blockIdx.x*256 + threadIdx.x;   // 1064960
  if (idx < 524288) W2bf[idx] = f2bf(W2[idx]);
  else if (idx < 655360){ int i = idx - 524288; W1bf[i] = f2bf(W1[i]); }
  else if (idx < 786432){ int i = idx - 655360; int k = i >> 7, h = i & 127;
    W1Tbf[i] = f2bf(W1[h*ZD_ + k]); }
  else if (idx < 802816){ int i = idx - 786432; Mbf[i] = f2bf(Mm[i]); }
  else { int i = idx - 802816; int j = i >> 10, k = i & 1023;
    FBT[i] = f2bf(j < H_ ? W1[j*ZD_ + k] : R[(size_t)(j-H_)*ZD_ + k]); }
}

// ---------------- x-pass (MFMA, dbuf, 1 barrier/iter): [cneg | h1pre] = x @ WXT^T ----
// BM=32, BN=128, grid 512, 256 thr. Carried-register prefetch, unroll 1 (no hoist-spill).
__global__ __launch_bounds__(256) void k_xpass_mfma(
    const float* __restrict__ x, const ushort* __restrict__ WXT,
    const float* __restrict__ cb, const float* __restrict__ q0,
    float* __restrict__ cneg, float* __restrict__ h1pre){
  __shared__ __align__(16) ushort xt[2][32*72];
  __shared__ __align__(16) ushort bt[2][128*72];
  const int t = threadIdx.x, lane = t & 63, w = t >> 6;
  const int bm = blockIdx.x >> 1, bn = blockIdx.x & 1;
  const int row0 = bm*32, ncol0 = bn*128;
  const int l15 = lane & 15, kq8 = (lane >> 4)*8, rq = (lane >> 4)*4;
  const int rt = w & 1, cb4 = (w >> 1)*4;
  const int xr = t >> 3, xk = (t & 7)*8;
  const int wn = t >> 1, wk = (t & 1)*32;
  f32x4_t acc[4] = {};
  // prologue: tile 0 direct
  {
    float4 v0 = *(const float4*)&x[(size_t)(row0+xr)*XD_ + xk];
    float4 v1 = *(const float4*)&x[(size_t)(row0+xr)*XD_ + xk + 4];
    union { ushort u[8]; uint4 q; } p;
    p.u[0]=f2bf(v0.x); p.u[1]=f2bf(v0.y); p.u[2]=f2bf(v0.z); p.u[3]=f2bf(v0.w);
    p.u[4]=f2bf(v1.x); p.u[5]=f2bf(v1.y); p.u[6]=f2bf(v1.z); p.u[7]=f2bf(v1.w);
    *(uint4*)&xt[0][xr*72 + xk] = p.q;
    const ushort* s = &WXT[(size_t)(ncol0+wn)*XD_ + wk];
    uint4 b0v=*(const uint4*)s, b1v=*(const uint4*)(s+8), b2v=*(const uint4*)(s+16), b3v=*(const uint4*)(s+24);
    ushort* d = &bt[0][wn*72 + wk];
    *(uint4*)d=b0v; *(uint4*)(d+8)=b1v; *(uint4*)(d+16)=b2v; *(uint4*)(d+24)=b3v;
  }
  // carried prefetch: tile 1
  float4 xv0, xv1; uint4 wb0, wb1, wb2, wb3;
  {
    xv0 = *(const float4*)&x[(size_t)(row0+xr)*XD_ + 64 + xk];
    xv1 = *(const float4*)&x[(size_t)(row0+xr)*XD_ + 64 + xk + 4];
    const ushort* s = &WXT[(size_t)(ncol0+wn)*XD_ + 64 + wk];
    wb0=*(const uint4*)s; wb1=*(const uint4*)(s+8); wb2=*(const uint4*)(s+16); wb3=*(const uint4*)(s+24);
  }
  #pragma unroll 1
  for (int it = 0; it < 64; ++it){
    __syncthreads();
    if (it < 63){
      union { ushort u[8]; uint4 q; } p;
      p.u[0]=f2bf(xv0.x); p.u[1]=f2bf(xv0.y); p.u[2]=f2bf(xv0.z); p.u[3]=f2bf(xv0.w);
      p.u[4]=f2bf(xv1.x); p.u[5]=f2bf(xv1.y); p.u[6]=f2bf(xv1.z); p.u[7]=f2bf(xv1.w);
      *(uint4*)&xt[(it+1)&1][xr*72 + xk] = p.q;
      ushort* d = &bt[(it+1)&1][wn*72 + wk];
      *(uint4*)d=wb0; *(uint4*)(d+8)=wb1; *(uint4*)(d+16)=wb2; *(uint4*)(d+24)=wb3;
    }
    if (it < 62){
      const int kt = (it+2)*64;
      xv0 = *(const float4*)&x[(size_t)(row0+xr)*XD_ + kt + xk];
      xv1 = *(const float4*)&x[(size_t)(row0+xr)*XD_ + kt + xk + 4];
      const ushort* s = &WXT[(size_t)(ncol0+wn)*XD_ + kt + wk];
      wb0=*(const uint4*)s; wb1=*(const uint4*)(s+8); wb2=*(const uint4*)(s+16); wb3=*(const uint4*)(s+24);
    }
    const ushort* xb = &xt[it&1][(rt*16+l15)*72];
    const ushort* bb = &bt[it&1][0];
    #pragma unroll
    for (int h = 0; h < 2; ++h){
      short8_t a = *(const short8_t*)(xb + h*32 + kq8);
      #pragma unroll
      for (int c = 0; c < 4; ++c){
        short8_t b = *(const short8_t*)(bb + ((cb4+c)*16+l15)*72 + h*32 + kq8);
        acc[c] = MFMA16(a, b, acc[c]);
      }
    }
  }
  #pragma unroll
  for (int c = 0; c < 4; ++c){
    int jl = (cb4+c)*16 + l15;
    #pragma unroll
    for (int r = 0; r < 4; ++r){
      int row = row0 + rt*16 + rq + r;
      float v = acc[c][r];
      if (bn == 0) cneg[(size_t)row*H_ + jl] = 2.0f*(cb[jl] - v);
      else         h1pre[(size_t)row*H_ + jl] = v + q0[jl];
    }
  }
}

// ---------------- fused Langevin: init + 10 steps + finalz; z in LDS (f32 + bf16 shadow) --
// grid 512 x 512 thr (8 waves), BM=16. R7 lesson: full unroll hoisted many iterations'
// global-load prefetches -> >128 VGPR -> residual spill (WRITE 87MB). Fix: unroll 1 +
// carried-register prefetch (1 tile in flight). bf16 z shadow kills P1/finalz pack
// conversions (pure ds_read_b128 -> MFMA). LDS total 144,384 B (1 block/CU).
__global__ __launch_bounds__(512) void k_langevin(
    const ushort* __restrict__ W1bf, const ushort* __restrict__ W1Tbf,
    const ushort* __restrict__ Mbf, const ushort* __restrict__ FBT,
    const float* __restrict__ b1, const float* __restrict__ r0v,
    const float* __restrict__ cneg, const uint32_t* __restrict__ dkeys,
    ushort* __restrict__ hfin_bf, float* __restrict__ capre){
  __shared__ __align__(16) float  zlds[16][1028];      // 65792 B (f32 master)
  __shared__ __align__(16) ushort zbf[16][1032];       // 33024 B (bf16 shadow)
  __shared__ __align__(16) ushort ws_[2][128*72];      // 36864 B
  __shared__ __align__(16) ushort abuf[16*136];        //  4352 B
  __shared__ __align__(16) ushort glbuf[16*136];       //  4352 B

  const int t = threadIdx.x, lane = t & 63, w = t >> 6;
  const int l15 = lane & 15, kq8 = (lane >> 4)*8, rq = (lane >> 4)*4;
  const int b0 = blockIdx.x * 16;
  const int myc = w*16 + l15;

  // ---- z0 init (RNG) into LDS (both copies)
  {
    const uint32_t k0 = dkeys[0], k1 = dkeys[1];
    const int row16 = t >> 5, c4 = (t & 31)*4;
    #pragma unroll 1
    for (int i = 0; i < 8; ++i){
      const int col = c4 + 128*i;
      uint32_t base = (uint32_t)(b0 + row16)*1024u + (uint32_t)col;
      float4 v;
      v.x = rng_normal(k0,k1,base+0);
      v.y = rng_normal(k0,k1,base+1);
      v.z = rng_normal(k0,k1,base+2);
      v.w = rng_normal(k0,k1,base+3);
      *(float4*)&zlds[row16][col] = v;
      ushort4 b4; b4.x=f2bf(v.x); b4.y=f2bf(v.y); b4.z=f2bf(v.z); b4.w=f2bf(v.w);
      *(ushort4*)&zbf[row16][col] = b4;
    }
  }
  const float bb = b1[myc];
  float cn[4];
  #pragma unroll
  for (int r = 0; r < 4; ++r) cn[r] = cneg[(size_t)(b0+rq+r)*H_ + myc];

  const int wr = t >> 2, wk4 = (t & 3)*16;     // 128-row x 64-col weight tile coords
  const int kk3 = (t & 3)*32;                  // 128-row x 128-col (P3) coords

  #pragma unroll 1
  for (int s = 0; s < 10; ++s){
    const uint32_t nk0 = dkeys[2+2*s], nk1 = dkeys[3+2*s];
    // ---------- P1: h = z @ W1^T (K=1024, dbuf, 1 barrier/iter, carried prefetch)
    {
      const ushort* sw = &W1bf[(size_t)wr*ZD_ + wk4];
      uint4 a0 = *(const uint4*)sw, a1 = *(const uint4*)(sw+8);
      ushort* d = &ws_[0][wr*72 + wk4];
      *(uint4*)d = a0; *(uint4*)(d+8) = a1;
    }
    uint4 p0, p1;
    {
      const ushort* sw = &W1bf[(size_t)wr*ZD_ + 64 + wk4];
      p0 = *(const uint4*)sw; p1 = *(const uint4*)(sw+8);
    }
    f32x4_t acc = {};
    #pragma unroll 1
    for (int it = 0; it < 16; ++it){
      __syncthreads();
      if (it < 15){
        ushort* d = &ws_[(it+1)&1][wr*72 + wk4];
        *(uint4*)d = p0; *(uint4*)(d+8) = p1;
      }
      if (it < 14){
        const ushort* sw = &W1bf[(size_t)wr*ZD_ + (it+2)*64 + wk4];
        p0 = *(const uint4*)sw; p1 = *(const uint4*)(sw+8);
      }
      const ushort* wsb = &ws_[it&1][myc*72];
      #pragma unroll
      for (int h = 0; h < 2; ++h){
        short8_t av = *(const short8_t*)&zbf[l15][it*64 + h*32 + kq8];
        short8_t bv = *(const short8_t*)(wsb + h*32 + kq8);
        acc = MFMA16(av, bv, acc);
      }
    }
    float hv[4];
    #pragma unroll
    for (int r = 0; r < 4; ++r){
      hv[r] = acc[r] + bb;
      abuf[(rq+r)*136 + myc] = f2bf(hv[r] > 0.f ? hv[r] : 0.f);
    }
    __syncthreads();           // abuf ready; P1 ws reads done
    // ---------- stage M into ws_[0]/ws_[1]
    {
      const ushort* sm = &Mbf[(size_t)wr*H_ + kk3];
      uint4 m0=*(const uint4*)sm, m1=*(const uint4*)(sm+8), m2=*(const uint4*)(sm+16), m3=*(const uint4*)(sm+24);
      ushort* d = &ws_[kk3>>6][wr*72 + (kk3&63)];
      *(uint4*)d=m0; *(uint4*)(d+8)=m1; *(uint4*)(d+16)=m2; *(uint4*)(d+24)=m3;
    }
    __syncthreads();
    // ---------- P2: g2 = a @ M
    f32x4_t acc2 = {};
    #pragma unroll
    for (int c = 0; c < 2; ++c)
      #pragma unroll
      for (int h = 0; h < 2; ++h){
        short8_t av = *(const short8_t*)&abuf[l15*136 + c*64 + h*32 + kq8];
        short8_t bv = *(const short8_t*)&ws_[c][myc*72 + h*32 + kq8];
        acc2 = MFMA16(av, bv, acc2);
      }
    #pragma unroll
    for (int r = 0; r < 4; ++r){
      float g = (hv[r] > 0.f) ? fmaf(2.f, acc2[r], cn[r]) : 0.f;
      glbuf[(rq+r)*136 + myc] = f2bf(g);
    }
    // ---------- P3: z -= 0.005*(g @ W1) + 0.1*noise ; carried prefetch, 2 barriers/tile
    uint4 v0, v1, v2, v3;
    {
      const ushort* sw = &W1Tbf[(size_t)wr*H_ + kk3];
      v0=*(const uint4*)sw; v1=*(const uint4*)(sw+8); v2=*(const uint4*)(sw+16); v3=*(const uint4*)(sw+24);
    }
    #pragma unroll 1
    for (int nt = 0; nt < 8; ++nt){
      __syncthreads();         // prev MFMA ws reads done; glbuf visible (nt=0)
      {
        ushort* d = &ws_[kk3>>6][wr*72 + (kk3&63)];
        *(uint4*)d=v0; *(uint4*)(d+8)=v1; *(uint4*)(d+16)=v2; *(uint4*)(d+24)=v3;
      }
      if (nt < 7){
        const ushort* sw = &W1Tbf[(size_t)((nt+1)*128 + wr)*H_ + kk3];
        v0=*(const uint4*)sw; v1=*(const uint4*)(sw+8); v2=*(const uint4*)(sw+16); v3=*(const uint4*)(sw+24);
      }
      __syncthreads();         // ws ready
      f32x4_t acc3 = {};
      #pragma unroll
      for (int c = 0; c < 2; ++c)
        #pragma unroll
        for (int h = 0; h < 2; ++h){
          short8_t av = *(const short8_t*)&glbuf[l15*136 + c*64 + h*32 + kq8];
          short8_t bv = *(const short8_t*)&ws_[c][myc*72 + h*32 + kq8];
          acc3 = MFMA16(av, bv, acc3);
        }
      const int col = nt*128 + myc;
      #pragma unroll
      for (int r = 0; r < 4; ++r){
        const int row = rq + r;
        uint32_t idx = (uint32_t)(b0+row)*1024u + (uint32_t)col;
        float t2 = fmaf(-0.005f, acc3[r], zlds[row][col]);
        float zn = fmaf(0.1f, rng_normal(nk0,nk1,idx), t2);
        zlds[row][col] = zn;
        zbf[row][col] = f2bf(zn);
      }
    }
    __syncthreads();           // z updates visible; last ws reads done
  }

  // ---------- finalz: [hfin | capre] = z @ FBT^T  (K=1024, N=256)
  f32x4_t fac0 = {}, fac1 = {};
  const int n2 = t >> 1, kh = (t & 1)*32;
  uint4 c0, c1, c2, c3;
  {
    const ushort* sf = &FBT[(size_t)n2*ZD_ + kh];
    c0=*(const uint4*)sf; c1=*(const uint4*)(sf+8); c2=*(const uint4*)(sf+16); c3=*(const uint4*)(sf+24);
  }
  #pragma unroll 1
  for (int it = 0; it < 16; ++it){
    __syncthreads();           // prev MFMA ws reads done
    {
      ushort* d = (n2 < 128) ? &ws_[0][n2*72 + kh] : &ws_[1][(n2-128)*72 + kh];
      *(uint4*)d=c0; *(uint4*)(d+8)=c1; *(uint4*)(d+16)=c2; *(uint4*)(d+24)=c3;
    }
    if (it < 15){
      const ushort* sf = &FBT[(size_t)n2*ZD_ + (it+1)*64 + kh];
      c0=*(const uint4*)sf; c1=*(const uint4*)(sf+8); c2=*(const uint4*)(sf+16); c3=*(const uint4*)(sf+24);
    }
    __syncthreads();
    #pragma unroll
    for (int h = 0; h < 2; ++h){
      short8_t av = *(const short8_t*)&zbf[l15][it*64 + h*32 + kq8];
      short8_t bv0 = *(const short8_t*)&ws_[0][myc*72 + h*32 + kq8];
      fac0 = MFMA16(av, bv0, fac0);
      short8_t bv1 = *(const short8_t*)&ws_[1][myc*72 + h*32 + kq8];
      fac1 = MFMA16(av, bv1, fac1);
    }
  }
  {
    const float rv = r0v[myc];
    #pragma unroll
    for (int r = 0; r < 4; ++r){
      int row = b0 + rq + r;
      float h0 = fac0[r] + bb;
      hfin_bf[(size_t)row*H_ + myc] = f2bf(h0 > 0.f ? h0 : 0.f);
      capre[(size_t)row*H_ + myc] = fac1[r] + rv;
    }
  }
}

// ---------------- x_recon (MFMA): out = hfin @ W2^T + b2 ----------------
__global__ __launch_bounds__(256) void k_xrecon_mfma(
    const ushort* __restrict__ hfin_bf, const ushort* __restrict__ W2bf,
    const float* __restrict__ b2, float* __restrict__ out){
  __shared__ __align__(16) ushort at[64*136];
  __shared__ __align__(16) ushort bt[128*136];
  const int tid = threadIdx.x, lane = tid & 63, w = tid >> 6;
  const int bm = blockIdx.x >> 5, bn = blockIdx.x & 31;
  const int row0 = bm*64, c0 = bn*128;
  const int l15 = lane & 15, kq8 = (lane >> 4)*8, rq = (lane >> 4)*4;
  { int r = tid >> 2, kq = (tid & 3)*32;
    const ushort* src = &hfin_bf[(size_t)(row0 + r)*H_ + kq];
    #pragma unroll
    for (int i = 0; i < 4; ++i) *(uint4*)&at[r*136 + kq + 8*i] = *(const uint4*)(src + 8*i);
  }
  { int n = tid >> 1, kh = (tid & 1)*64;
    const ushort* src = &W2bf[(size_t)(c0 + n)*H_ + kh];
    #pragma unroll
    for (int i = 0; i < 8; ++i) *(uint4*)&bt[n*136 + kh + 8*i] = *(const uint4*)(src + 8*i);
  }
  __syncthreads();
  f32x4_t acc[8] = {};
  #pragma unroll
  for (int k = 0; k < 4; ++k){
    short8_t a = *(const short8_t*)&at[(w*16 + l15)*136 + k*32 + kq8];
    #pragma unroll
    for (int nf = 0; nf < 8; ++nf){
      short8_t b = *(const short8_t*)&bt[(nf*16 + l15)*136 + k*32 + kq8];
      acc[nf] = MFMA16(a, b, acc[nf]);
    }
  }
  #pragma unroll
  for (int nf = 0; nf < 8; ++nf){
    int c = c0 + nf*16 + l15;
    float bbv = b2[c];
    #pragma unroll
    for (int r = 0; r < 4; ++r){
      int row = row0 + w*16 + rq + r;
      out[(size_t)row*XD_ + c] = acc[nf][r] + bbv;
    }
  }
}

// ---------------- per-row transformer tail -> y_pred ----------------
__device__ __forceinline__ float wsum64(float v){
  #pragma unroll
  for (int off = 32; off > 0; off >>= 1) v += __shfl_xor(v, off, 64);
  return v;
}

__global__ __launch_bounds__(256) void k_tail(
    const float* __restrict__ h1pre, const float* __restrict__ capre,
    const float* __restrict__ ln1g, const float* __restrict__ ln1b,
    const float* __restrict__ ln2g, const float* __restrict__ ln2b,
    const float* __restrict__ ln3g, const float* __restrict__ ln3b,
    const float* __restrict__ fW1, const float* __restrict__ fb1,
    const float* __restrict__ fW2, const float* __restrict__ fb2,
    const float* __restrict__ outW, const float* __restrict__ outb,
    float* __restrict__ y){
  __shared__ float sh2[4][128];
  __shared__ float st1[4][128];
  const int tid = threadIdx.x;
  const int w = tid >> 6;
  const int l = tid & 63;
  const int b = blockIdx.x * 4 + w;
  const float* hp = h1pre + (size_t)b * H_;
  const float* cp = capre + (size_t)b * H_;
  float x0 = hp[l], x1 = hp[l+64];
  float m = wsum64(x0 + x1) * (1.0f/128.0f);
  float d0 = x0 - m, d1 = x1 - m;
  float v = wsum64(d0*d0 + d1*d1) * (1.0f/128.0f);
  float rs = rsqrtf(v + 1e-5f);
  float h1a = d0 * rs * ln1g[l]    + ln1b[l];
  float h1b = d1 * rs * ln1g[l+64] + ln1b[l+64];
  x0 = h1a + cp[l]; x1 = h1b + cp[l+64];
  m = wsum64(x0 + x1) * (1.0f/128.0f);
  d0 = x0 - m; d1 = x1 - m;
  v = wsum64(d0*d0 + d1*d1) * (1.0f/128.0f);
  rs = rsqrtf(v + 1e-5f);
  float h2a = d0 * rs * ln2g[l]    + ln2b[l];
  float h2b = d1 * rs * ln2g[l+64] + ln2b[l+64];
  sh2[w][l] = h2a; sh2[w][l+64] = h2b;
  __syncthreads();
  float ta = fb1[l], tb = fb1[l+64];
  #pragma unroll 8
  for (int m4 = 0; m4 < H_; m4 += 4){
    float4 hv = *(const float4*)&sh2[w][m4];
    float4 wa = *(const float4*)&fW1[(size_t)l*H_ + m4];
    float4 wb = *(const float4*)&fW1[(size_t)(l+64)*H_ + m4];
    ta = fmaf(wa.x, hv.x, ta); ta = fmaf(wa.y, hv.y, ta); ta = fmaf(wa.z, hv.z, ta); ta = fmaf(wa.w, hv.w, ta);
    tb = fmaf(wb.x, hv.x, tb); tb = fmaf(wb.y, hv.y, tb); tb = fmaf(wb.z, hv.z, tb); tb = fmaf(wb.w, hv.w, tb);
  }
  ta = fmaxf(ta, 0.0f); tb = fmaxf(tb, 0.0f);
  st1[w][l] = ta; st1[w][l+64] = tb;
  __syncthreads();
  float fa = fb2[l], fbv = fb2[l+64];
  #pragma unroll 8
  for (int m4 = 0; m4 < H_; m4 += 4){
    float4 tv = *(const float4*)&st1[w][m4];
    float4 wa = *(const float4*)&fW2[(size_t)l*H_ + m4];
    float4 wb = *(const float4*)&fW2[(size_t)(l+64)*H_ + m4];
    fa  = fmaf(wa.x, tv.x, fa);  fa  = fmaf(wa.y, tv.y, fa);  fa  = fmaf(wa.z, tv.z, fa);  fa  = fmaf(wa.w, tv.w, fa);
    fbv = fmaf(wb.x, tv.x, fbv); fbv = fmaf(wb.y, tv.y, fbv); fbv = fmaf(wb.z, tv.z, fbv); fbv = fmaf(wb.w, tv.w, fbv);
  }
  x0 = h2a + fa; x1 = h2b + fbv;
  m = wsum64(x0 + x1) * (1.0f/128.0f);
  d0 = x0 - m; d1 = x1 - m;
  v = wsum64(d0*d0 + d1*d1) * (1.0f/128.0f);
  rs = rsqrtf(v + 1e-5f);
  float h3a = d0 * rs * ln3g[l]    + ln3b[l];
  float h3b = d1 * rs * ln3g[l+64] + ln3b[l+64];
  float py = wsum64(outW[l]*h3a + outW[l+64]*h3b);
  if (l == 0) y[b] = py + outb[0];
}

// ---------------- host ----------------
extern "C" void kernel_launch(void* const* d_in, const int* in_sizes, int n_in,
                              void* d_out, int out_size, void* d_ws, size_t ws_size,
                              hipStream_t stream){
  const float* x      = (const float*)d_in[0];
  const float* pxW1   = (const float*)d_in[1];
  const float* pxb1   = (const float*)d_in[2];
  const float* pxW2   = (const float*)d_in[3];
  const float* pxb2   = (const float*)d_in[4];
  const float* embW   = (const float*)d_in[5];
  const float* embb   = (const float*)d_in[6];
  const float* xpW    = (const float*)d_in[7];
  const float* xpb    = (const float*)d_in[8];
  const float* zpW    = (const float*)d_in[9];
  const float* zpb    = (const float*)d_in[10];
  const float* saWqkv = (const float*)d_in[11];
  const float* sabqkv = (const float*)d_in[12];
  const float* saWo   = (const float*)d_in[13];
  const float* sabo   = (const float*)d_in[14];
  const float* caWqkv = (const float*)d_in[15];
  const float* cabqkv = (const float*)d_in[16];
  const float* caWo   = (const float*)d_in[17];
  const float* cabo   = (const float*)d_in[18];
  const float* fW1    = (const float*)d_in[19];
  const float* fb1    = (const float*)d_in[20];
  const float* fW2    = (const float*)d_in[21];
  const float* fb2    = (const float*)d_in[22];
  const float* ln1g   = (const float*)d_in[23];
  const float* ln1b   = (const float*)d_in[24];
  const float* ln2g   = (const float*)d_in[25];
  const float* ln2b   = (const float*)d_in[26];
  const float* ln3g   = (const float*)d_in[27];
  const float* ln3b   = (const float*)d_in[28];
  const float* outW   = (const float*)d_in[29];
  const float* outb   = (const float*)d_in[30];
  (void)in_sizes; (void)n_in; (void)out_size; (void)ws_size;

  float* ws    = (float*)d_ws;
  float* cneg  = ws;                          // 1048576
  float* h1pre = cneg + (size_t)B_*H_;        // 1048576
  float* capre = h1pre + (size_t)B_*H_;       // 1048576
  float* Rm    = capre + (size_t)B_*H_;       // 131072
  float* Mm    = Rm + (size_t)H_*ZD_;         // 16384
  float* Sm    = Mm + H_*H_;                  // 16384
  float* Um    = Sm + H_*H_;                  // 16384
  float* Tm    = Um + H_*H_;                  // 8192
  float* vs0   = Tm + H_*XE_;
  float* vu0   = vs0 + H_;
  float* vt0   = vu0 + H_;
  float* vq0   = vt0 + H_;
  float* vr0   = vq0 + H_;
  float* vcb   = vr0 + H_;
  uint32_t* dkeys = (uint32_t*)(vcb + H_);    // 32 u32
  ushort* WXT   = (ushort*)(dkeys + 32);      // 1048576
  ushort* W2bf  = WXT + (size_t)256*XD_;      // 524288
  ushort* W1bf  = W2bf + (size_t)XD_*H_;      // 131072
  ushort* W1Tbf = W1bf + (size_t)H_*ZD_;      // 131072
  ushort* Mbf   = W1Tbf + (size_t)ZD_*H_;     // 16384
  ushort* FBT   = Mbf + H_*H_;                // 262144
  ushort* hfin  = FBT + (size_t)256*ZD_;      // 1048576

  float* xre   = (float*)d_out;
  float* ypred = xre + (size_t)B_*XD_;

  k_prepA   <<<512,  64, 0, stream>>>(saWo, saWqkv, caWo, caWqkv, Sm, Um);
  k_prepB   <<<6,    64, 0, stream>>>(saWo, sabqkv, sabo, caWo, cabqkv, cabo, pxW2, pxb2,
                                      vs0, vu0, vcb, dkeys);
  k_prepM   <<<256,  64, 0, stream>>>(pxW2, Mm);
  k_prepTR  <<<2180, 64, 0, stream>>>(Sm, Um, xpW, zpW, xpb, zpb, vs0, vu0, Tm, Rm, vt0, vr0);
  k_prepWXT <<<4096, 256, 0, stream>>>(pxW2, Tm, embW, embb, vt0, WXT, vq0);
  k_conv    <<<4160, 256, 0, stream>>>(pxW2, pxW1, Mm, Rm, W2bf, W1bf, W1Tbf, Mbf, FBT);
  k_xpass_mfma <<<512, 256, 0, stream>>>(x, WXT, vcb, vq0, cneg, h1pre);
  k_langevin <<<512, 512, 0, stream>>>(W1bf, W1Tbf, Mbf, FBT, pxb1, vr0, cneg, dkeys, hfin, capre);
  k_xrecon_mfma <<<4096, 256, 0, stream>>>(hfin, W2bf, pxb2, xre);
  k_tail    <<<2048, 256, 0, stream>>>(h1pre, capre, ln1g, ln1b, ln2g, ln2b, ln3g, ln3b,
                                       fW1, fb1, fW2, fb2, outW, outb, ypred);
}

// Round 9
// 900.210 us; speedup vs baseline: 1.6511x; 1.0218x over previous
//
#include <hip/hip_runtime.h>
#include <hip/hip_bf16.h>
#include <cstdint>
#include <cstddef>
#include <cmath>

#define B_     8192
#define XD_    4096
#define ZD_    1024
#define XE_    64
#define H_     128
#define ZN_    (B_*ZD_)

typedef __attribute__((ext_vector_type(8))) short short8_t;   // 8 x bf16 (4 VGPR)
typedef __attribute__((ext_vector_type(4))) float f32x4_t;    // MFMA accumulator
#define MFMA16(a,b,c) __builtin_amdgcn_mfma_f32_16x16x32_bf16((a),(b),(c),0,0,0)

// ---------------- threefry2x32 (bit-exact vs JAX, partitionable mode — validated R1-R8) ----
__host__ __device__ __forceinline__ uint32_t rotl32_(uint32_t x, int r){ return (x<<r)|(x>>(32-r)); }

__host__ __device__ __forceinline__ void tf2x32(uint32_t k0, uint32_t k1,
                                                uint32_t x0, uint32_t x1,
                                                uint32_t* o0, uint32_t* o1){
  uint32_t k2 = k0 ^ k1 ^ 0x1BD11BDAu;
  x0 += k0; x1 += k1;
  x0 += x1; x1 = rotl32_(x1,13); x1 ^= x0;
  x0 += x1; x1 = rotl32_(x1,15); x1 ^= x0;
  x0 += x1; x1 = rotl32_(x1,26); x1 ^= x0;
  x0 += x1; x1 = rotl32_(x1, 6); x1 ^= x0;
  x0 += k1; x1 += k2 + 1u;
  x0 += x1; x1 = rotl32_(x1,17); x1 ^= x0;
  x0 += x1; x1 = rotl32_(x1,29); x1 ^= x0;
  x0 += x1; x1 = rotl32_(x1,16); x1 ^= x0;
  x0 += x1; x1 = rotl32_(x1,24); x1 ^= x0;
  x0 += k2; x1 += k0 + 2u;
  x0 += x1; x1 = rotl32_(x1,13); x1 ^= x0;
  x0 += x1; x1 = rotl32_(x1,15); x1 ^= x0;
  x0 += x1; x1 = rotl32_(x1,26); x1 ^= x0;
  x0 += x1; x1 = rotl32_(x1, 6); x1 ^= x0;
  x0 += k0; x1 += k1 + 3u;
  x0 += x1; x1 = rotl32_(x1,17); x1 ^= x0;
  x0 += x1; x1 = rotl32_(x1,29); x1 ^= x0;
  x0 += x1; x1 = rotl32_(x1,16); x1 ^= x0;
  x0 += x1; x1 = rotl32_(x1,24); x1 ^= x0;
  x0 += k1; x1 += k2 + 4u;
  x0 += x1; x1 = rotl32_(x1,13); x1 ^= x0;
  x0 += x1; x1 = rotl32_(x1,15); x1 ^= x0;
  x0 += x1; x1 = rotl32_(x1,26); x1 ^= x0;
  x0 += x1; x1 = rotl32_(x1, 6); x1 ^= x0;
  x0 += k2; x1 += k0 + 5u;
  *o0 = x0; *o1 = x1;
}

// XLA ErfInv32; fast v_log (validated R8, absmax unchanged)
__device__ __forceinline__ float erfinv_(float x){
  float w = -__logf(fmaf(-x, x, 1.0f));
  float p;
  if (w < 5.0f){
    w -= 2.5f;
    p = 2.81022636e-08f;
    p = fmaf(p, w, 3.43273939e-07f);
    p = fmaf(p, w, -3.5233877e-06f);
    p = fmaf(p, w, -4.39150654e-06f);
    p = fmaf(p, w, 0.00021858087f);
    p = fmaf(p, w, -0.00125372503f);
    p = fmaf(p, w, -0.00417768164f);
    p = fmaf(p, w, 0.246640727f);
    p = fmaf(p, w, 1.50140941f);
  } else {
    w = sqrtf(w) - 3.0f;
    p = -0.000200214257f;
    p = fmaf(p, w, 0.000100950558f);
    p = fmaf(p, w, 0.00134934322f);
    p = fmaf(p, w, -0.00367342844f);
    p = fmaf(p, w, 0.00573950773f);
    p = fmaf(p, w, -0.0076224613f);
    p = fmaf(p, w, 0.00943887047f);
    p = fmaf(p, w, 1.00167406f);
    p = fmaf(p, w, 2.83297682f);
  }
  return p * x;
}

__device__ __forceinline__ float bits_to_normal(uint32_t bits){
  float f = __uint_as_float((bits >> 9) | 0x3f800000u) - 1.0f;
  float u = fmaxf(-0.99999994f, fmaf(f, 2.0f, -0.99999994f));
  return 1.41421356f * erfinv_(u);
}

__device__ __forceinline__ float rng_normal(uint32_t k0, uint32_t k1, uint32_t idx){
  uint32_t o0, o1; tf2x32(k0, k1, 0u, idx, &o0, &o1);
  return bits_to_normal(o0 ^ o1);
}

__device__ __forceinline__ ushort f2bf(float f){
  return __builtin_bit_cast(ushort, __float2bfloat16(f));
}
__device__ __forceinline__ float bf2f(ushort u){ return __uint_as_float(((uint32_t)u) << 16); }

// ---------------- weight-prep kernels (f32) ----------------
__global__ void k_prepA(const float* __restrict__ saWo, const float* __restrict__ saWqkv,
                        const float* __restrict__ caWo, const float* __restrict__ caWqkv,
                        float* __restrict__ S, float* __restrict__ U){
  int blk = blockIdx.x, tid = threadIdx.x;
  int idx = (blk & 255) * 64 + tid;
  int i = idx >> 7, j = idx & 127;
  if (blk < 256){
    float acc = (i == j) ? 1.0f : 0.0f;
    for (int k = 0; k < H_; ++k) acc += saWo[i*H_ + k] * saWqkv[(2*H_ + k)*H_ + j];
    S[idx] = acc;
  } else {
    float acc = 0.0f;
    for (int k = 0; k < H_; ++k) acc += caWo[i*H_ + k] * caWqkv[(2*H_ + k)*H_ + j];
    U[idx] = acc;
  }
}

__global__ void k_prepB(const float* __restrict__ saWo, const float* __restrict__ sabqkv, const float* __restrict__ sabo,
                        const float* __restrict__ caWo, const float* __restrict__ cabqkv, const float* __restrict__ cabo,
                        const float* __restrict__ W2, const float* __restrict__ pb2,
                        float* __restrict__ s0, float* __restrict__ u0, float* __restrict__ cb,
                        uint32_t* __restrict__ dkeys){
  int blk = blockIdx.x, tid = threadIdx.x;
  if (blk == 0 && tid == 0){
    for (uint32_t i = 0; i < 11; ++i){
      uint32_t a, b; tf2x32(0u, 42u, 0u, i, &a, &b);
      dkeys[2*i] = a; dkeys[2*i+1] = b;
    }
  }
  if (blk < 2){
    int i = blk*64 + tid;
    float acc = sabo[i];
    for (int k = 0; k < H_; ++k) acc += saWo[i*H_ + k] * sabqkv[2*H_ + k];
    s0[i] = acc;
  } else if (blk < 4){
    int i = (blk-2)*64 + tid;
    float acc = cabo[i];
    for (int k = 0; k < H_; ++k) acc += caWo[i*H_ + k] * cabqkv[2*H_ + k];
    u0[i] = acc;
  } else {
    int j = (blk-4)*64 + tid;
    float acc = 0.0f;
    for (int c = 0; c < XD_; ++c) acc += pb2[c] * W2[(size_t)c*H_ + j];
    cb[j] = acc;
  }
}

__global__ void k_prepM(const float* __restrict__ W2, float* __restrict__ M){
  int idx = blockIdx.x*64 + threadIdx.x;  // 16384
  int j1 = idx >> 7, j2 = idx & 127;
  float acc = 0.0f;
  for (int c = 0; c < XD_; ++c) acc += W2[(size_t)c*H_ + j1] * W2[(size_t)c*H_ + j2];
  M[idx] = acc;
}

__global__ void k_prepTR(const float* __restrict__ S, const float* __restrict__ U,
                         const float* __restrict__ xpW, const float* __restrict__ zpW,
                         const float* __restrict__ xpb, const float* __restrict__ zpb,
                         const float* __restrict__ s0, const float* __restrict__ u0,
                         float* __restrict__ T, float* __restrict__ R,
                         float* __restrict__ t0, float* __restrict__ r0v){
  int blk = blockIdx.x, tid = threadIdx.x;
  if (blk < 128){
    int idx = blk*64 + tid;
    int i = idx >> 6, e = idx & 63;
    float acc = 0.0f;
    for (int m = 0; m < H_; ++m) acc += S[i*H_ + m] * xpW[m*XE_ + e];
    T[idx] = acc;
  } else if (blk < 2176){
    int idx = (blk-128)*64 + tid;
    int i = idx >> 10, k = idx & 1023;
    float acc = 0.0f;
    for (int m = 0; m < H_; ++m) acc += U[i*H_ + m] * zpW[(size_t)m*ZD_ + k];
    R[idx] = acc;
  } else if (blk < 2178){
    int i = (blk-2176)*64 + tid;
    float acc = s0[i];
    for (int m = 0; m < H_; ++m) acc += S[i*H_ + m] * xpb[m];
    t0[i] = acc;
  } else {
    int i = (blk-2178)*64 + tid;
    float acc = u0[i];
    for (int m = 0; m < H_; ++m) acc += U[i*H_ + m] * zpb[m];
    r0v[i] = acc;
  }
}

__global__ void k_prepWXT(const float* __restrict__ W2, const float* __restrict__ T,
                          const float* __restrict__ embW, const float* __restrict__ embb,
                          const float* __restrict__ t0,
                          ushort* __restrict__ WXT, float* __restrict__ q0){
  int idx = blockIdx.x*256 + threadIdx.x;   // 1048576
  int j = idx >> 12, c = idx & 4095;
  float v;
  if (j < H_) v = W2[(size_t)c*H_ + j];
  else {
    int i = j - H_;
    float acc = 0.0f;
    for (int e = 0; e < XE_; ++e) acc += T[i*XE_ + e] * embW[(size_t)e*XD_ + c];
    v = acc;
  }
  WXT[idx] = f2bf(v);
  if (idx < H_){
    float acc = t0[idx];
    for (int e = 0; e < XE_; ++e) acc += T[idx*XE_ + e] * embb[e];
    q0[idx] = acc;
  }
}

// W2bf[524288], Mbf = 2*M [16384], FBT = [W1;R] [262144]
__global__ void k_conv(const float* __restrict__ W2, const float* __restrict__ W1,
                       const float* __restrict__ Mm, const float* __restrict__ R,
                       ushort* __restrict__ W2bf, ushort* __restrict__ Mbf,
                       ushort* __restrict__ FBT){
  int idx = blockIdx.x*256 + threadIdx.x;   // 802816
  if (idx < 524288) W2bf[idx] = f2bf(W2[idx]);
  else if (idx < 540672){ int i = idx - 524288; Mbf[i] = f2bf(2.0f*Mm[i]); }
  else { int i = idx - 540672; int j = i >> 10, k = i & 1023;
    FBT[i] = f2bf(j < H_ ? W1[j*ZD_ + k] : R[(size_t)(j-H_)*ZD_ + k]); }
}

// GGr [256][128] bf16: rows 0-127: -0.005*W1W1^T; rows 128-255: GGr[128+j][k] = -0.005*dot(W1[k],R[j])
__global__ void k_prepG(const float* __restrict__ W1, const float* __restrict__ R,
                        ushort* __restrict__ GGr){
  int idx = blockIdx.x*64 + threadIdx.x;   // 32768
  int i = idx >> 7, k = idx & 127;
  float acc = 0.0f;
  if (i < 128){
    for (int m = 0; m < ZD_; ++m) acc += W1[(size_t)i*ZD_ + m] * W1[(size_t)k*ZD_ + m];
  } else {
    for (int m = 0; m < ZD_; ++m) acc += W1[(size_t)k*ZD_ + m] * R[(size_t)(i-128)*ZD_ + m];
  }
  GGr[idx] = f2bf(-0.005f * acc);
}

// ---------------- x-pass (MFMA, dbuf, 1 barrier/iter): [cneg | h1pre] = x @ WXT^T ----
__global__ __launch_bounds__(256) void k_xpass_mfma(
    const float* __restrict__ x, const ushort* __restrict__ WXT,
    const float* __restrict__ cb, const float* __restrict__ q0,
    float* __restrict__ cneg, float* __restrict__ h1pre){
  __shared__ __align__(16) ushort xt[2][32*72];
  __shared__ __align__(16) ushort bt[2][128*72];
  const int t = threadIdx.x, lane = t & 63, w = t >> 6;
  const int bm = blockIdx.x >> 1, bn = blockIdx.x & 1;
  const int row0 = bm*32, ncol0 = bn*128;
  const int l15 = lane & 15, kq8 = (lane >> 4)*8, rq = (lane >> 4)*4;
  const int rt = w & 1, cb4 = (w >> 1)*4;
  const int xr = t >> 3, xk = (t & 7)*8;
  const int wn = t >> 1, wk = (t & 1)*32;
  f32x4_t acc[4] = {};
  {
    float4 v0 = *(const float4*)&x[(size_t)(row0+xr)*XD_ + xk];
    float4 v1 = *(const float4*)&x[(size_t)(row0+xr)*XD_ + xk + 4];
    union { ushort u[8]; uint4 q; } p;
    p.u[0]=f2bf(v0.x); p.u[1]=f2bf(v0.y); p.u[2]=f2bf(v0.z); p.u[3]=f2bf(v0.w);
    p.u[4]=f2bf(v1.x); p.u[5]=f2bf(v1.y); p.u[6]=f2bf(v1.z); p.u[7]=f2bf(v1.w);
    *(uint4*)&xt[0][xr*72 + xk] = p.q;
    const ushort* s = &WXT[(size_t)(ncol0+wn)*XD_ + wk];
    uint4 b0v=*(const uint4*)s, b1v=*(const uint4*)(s+8), b2v=*(const uint4*)(s+16), b3v=*(const uint4*)(s+24);
    ushort* d = &bt[0][wn*72 + wk];
    *(uint4*)d=b0v; *(uint4*)(d+8)=b1v; *(uint4*)(d+16)=b2v; *(uint4*)(d+24)=b3v;
  }
  float4 xv0, xv1; uint4 wb0, wb1, wb2, wb3;
  {
    xv0 = *(const float4*)&x[(size_t)(row0+xr)*XD_ + 64 + xk];
    xv1 = *(const float4*)&x[(size_t)(row0+xr)*XD_ + 64 + xk + 4];
    const ushort* s = &WXT[(size_t)(ncol0+wn)*XD_ + 64 + wk];
    wb0=*(const uint4*)s; wb1=*(const uint4*)(s+8); wb2=*(const uint4*)(s+16); wb3=*(const uint4*)(s+24);
  }
  #pragma unroll 1
  for (int it = 0; it < 64; ++it){
    __syncthreads();
    if (it < 63){
      union { ushort u[8]; uint4 q; } p;
      p.u[0]=f2bf(xv0.x); p.u[1]=f2bf(xv0.y); p.u[2]=f2bf(xv0.z); p.u[3]=f2bf(xv0.w);
      p.u[4]=f2bf(xv1.x); p.u[5]=f2bf(xv1.y); p.u[6]=f2bf(xv1.z); p.u[7]=f2bf(xv1.w);
      *(uint4*)&xt[(it+1)&1][xr*72 + xk] = p.q;
      ushort* d = &bt[(it+1)&1][wn*72 + wk];
      *(uint4*)d=wb0; *(uint4*)(d+8)=wb1; *(uint4*)(d+16)=wb2; *(uint4*)(d+24)=wb3;
    }
    if (it < 62){
      const int kt = (it+2)*64;
      xv0 = *(const float4*)&x[(size_t)(row0+xr)*XD_ + kt + xk];
      xv1 = *(const float4*)&x[(size_t)(row0+xr)*XD_ + kt + xk + 4];
      const ushort* s = &WXT[(size_t)(ncol0+wn)*XD_ + kt + wk];
      wb0=*(const uint4*)s; wb1=*(const uint4*)(s+8); wb2=*(const uint4*)(s+16); wb3=*(const uint4*)(s+24);
    }
    const ushort* xb = &xt[it&1][(rt*16+l15)*72];
    const ushort* bb = &bt[it&1][0];
    #pragma unroll
    for (int h = 0; h < 2; ++h){
      short8_t a = *(const short8_t*)(xb + h*32 + kq8);
      #pragma unroll
      for (int c = 0; c < 4; ++c){
        short8_t b = *(const short8_t*)(bb + ((cb4+c)*16+l15)*72 + h*32 + kq8);
        acc[c] = MFMA16(a, b, acc[c]);
      }
    }
  }
  #pragma unroll
  for (int c = 0; c < 4; ++c){
    int jl = (cb4+c)*16 + l15;
    #pragma unroll
    for (int r = 0; r < 4; ++r){
      int row = row0 + rt*16 + rq + r;
      float v = acc[c][r];
      if (bn == 0) cneg[(size_t)row*H_ + jl] = 2.0f*(cb[jl] - v);
      else         h1pre[(size_t)row*H_ + jl] = v + q0[jl];
    }
  }
}

// ---------------- noise projection: pass p rows n_p [8192][1024] (RNG) @ FBT^T -> [8192][256]
// p=0: z0 -> y0c0 (f32, unscaled). p=1..10: noise -> NWR[p-1] (bf16, x0.1).
// BM=64, 256 thr (4 waves), grid 11*128. A generated in-kernel; B read directly from L2.
__global__ __launch_bounds__(256) void k_noiseproj(
    const ushort* __restrict__ FBT, const uint32_t* __restrict__ dkeys,
    float* __restrict__ y0c0, ushort* __restrict__ NWR){
  __shared__ __align__(16) ushort at[64*72];
  const int t = threadIdx.x, lane = t & 63, w = t >> 6;
  const int l15 = lane & 15, kq8 = (lane >> 4)*8, rq = (lane >> 4)*4;
  const int p = blockIdx.x >> 7, mb = blockIdx.x & 127;
  const int gb0 = mb*64;
  const uint32_t k0 = dkeys[2*p], k1 = dkeys[2*p+1];
  const int arow = t >> 2, ak0 = (t & 3)*16;
  f32x4_t acc[16] = {};
  #pragma unroll 1
  for (int it = 0; it < 16; ++it){
    __syncthreads();                 // prior MFMA A-reads done
    {
      uint32_t base = (uint32_t)(gb0 + arow)*1024u + (uint32_t)(it*64 + ak0);
      union { ushort u[8]; uint4 q; } pk;
      #pragma unroll
      for (int j = 0; j < 8; ++j) pk.u[j] = f2bf(rng_normal(k0,k1,base+j));
      *(uint4*)&at[arow*72 + ak0] = pk.q;
      #pragma unroll
      for (int j = 0; j < 8; ++j) pk.u[j] = f2bf(rng_normal(k0,k1,base+8+j));
      *(uint4*)&at[arow*72 + ak0 + 8] = pk.q;
    }
    __syncthreads();                 // A ready
    #pragma unroll
    for (int h = 0; h < 2; ++h){
      short8_t a = *(const short8_t*)&at[(w*16+l15)*72 + h*32 + kq8];
      #pragma unroll
      for (int cf = 0; cf < 16; ++cf){
        short8_t b = *(const short8_t*)&FBT[(size_t)(cf*16+l15)*ZD_ + it*64 + h*32 + kq8];
        acc[cf] = MFMA16(a, b, acc[cf]);
      }
    }
  }
  #pragma unroll
  for (int cf = 0; cf < 16; ++cf){
    int col = cf*16 + l15;
    #pragma unroll
    for (int r = 0; r < 4; ++r){
      int row = gb0 + w*16 + rq + r;
      float v = acc[cf][r];
      if (p == 0) y0c0[(size_t)row*256 + col] = v;
      else NWR[(size_t)(p-1)*2097152 + (size_t)row*256 + col] = f2bf(0.1f*v);
    }
  }
}

// ---------------- 128-dim Langevin: yc state in f32 MFMA accumulators ----------------
// z eliminated: y=z@W1^T, c=z@R^T obey linear recurrences with precomputed 128x128 mats.
// grid 512 x 512 thr; 3 barriers/step; B-matrices (M2bf, GGr) read from L2 directly.
__global__ __launch_bounds__(512) void k_lv2(
    const ushort* __restrict__ M2bf, const ushort* __restrict__ GGr,
    const float* __restrict__ y0c0, const ushort* __restrict__ NWR,
    const float* __restrict__ b1, const float* __restrict__ r0v,
    const float* __restrict__ cneg,
    ushort* __restrict__ hfin_bf, float* __restrict__ capre){
  __shared__ __align__(16) ushort abuf[16*136];
  __shared__ __align__(16) ushort glbuf[16*136];
  const int t = threadIdx.x, lane = t & 63, w = t >> 6;
  const int l15 = lane & 15, kq8 = (lane >> 4)*8, rq = (lane >> 4)*4;
  const int b0 = blockIdx.x * 16;
  const int myc = w*16 + l15;
  const int col2 = w*32 + l15;       // nf=0 col in [0,256) yc-space

  f32x4_t acc[2];
  #pragma unroll
  for (int nf = 0; nf < 2; ++nf)
    #pragma unroll
    for (int r = 0; r < 4; ++r)
      acc[nf][r] = y0c0[(size_t)(b0+rq+r)*256 + col2 + nf*16];
  float cn[4];
  #pragma unroll
  for (int r = 0; r < 4; ++r) cn[r] = cneg[(size_t)(b0+rq+r)*H_ + myc];
  float bb2[2];
  bb2[0] = (w < 4) ? b1[col2] : 0.0f;
  bb2[1] = (w < 4) ? b1[col2+16] : 0.0f;
  ushort nx[8];
  #pragma unroll
  for (int nf = 0; nf < 2; ++nf)
    #pragma unroll
    for (int r = 0; r < 4; ++r)
      nx[nf*4+r] = NWR[(size_t)(b0+rq+r)*256 + col2 + nf*16];

  #pragma unroll 1
  for (int s = 0; s < 10; ++s){
    if (w < 4){
      #pragma unroll
      for (int nf = 0; nf < 2; ++nf)
        #pragma unroll
        for (int r = 0; r < 4; ++r)
          abuf[(rq+r)*136 + col2 + nf*16] = f2bf(fmaxf(acc[nf][r] + bb2[nf], 0.0f));
    }
    __syncthreads();
    // phase1: g2 = a @ (2M), K=128
    f32x4_t g2 = {};
    #pragma unroll
    for (int h = 0; h < 4; ++h){
      short8_t a = *(const short8_t*)&abuf[l15*136 + h*32 + kq8];
      short8_t b = *(const short8_t*)&M2bf[(size_t)myc*H_ + h*32 + kq8];
      g2 = MFMA16(a, b, g2);
    }
    #pragma unroll
    for (int r = 0; r < 4; ++r){
      float g = (abuf[(rq+r)*136 + myc] != 0) ? (g2[r] + cn[r]) : 0.0f;
      glbuf[(rq+r)*136 + myc] = f2bf(g);
    }
    __syncthreads();
    // phase2: yc += g @ [-0.005*G | -0.005*Gr], + 0.1*noise (pre-scaled)
    #pragma unroll
    for (int nf = 0; nf < 2; ++nf)
      #pragma unroll
      for (int h = 0; h < 4; ++h){
        short8_t a = *(const short8_t*)&glbuf[l15*136 + h*32 + kq8];
        short8_t b = *(const short8_t*)&GGr[(size_t)(col2 + nf*16)*H_ + h*32 + kq8];
        acc[nf] = MFMA16(a, b, acc[nf]);
      }
    #pragma unroll
    for (int nf = 0; nf < 2; ++nf)
      #pragma unroll
      for (int r = 0; r < 4; ++r)
        acc[nf][r] += bf2f(nx[nf*4+r]);
    if (s < 9){
      #pragma unroll
      for (int nf = 0; nf < 2; ++nf)
        #pragma unroll
        for (int r = 0; r < 4; ++r)
          nx[nf*4+r] = NWR[(size_t)(s+1)*2097152 + (size_t)(b0+rq+r)*256 + col2 + nf*16];
    }
    __syncthreads();
  }
  if (w < 4){
    #pragma unroll
    for (int nf = 0; nf < 2; ++nf)
      #pragma unroll
      for (int r = 0; r < 4; ++r)
        hfin_bf[(size_t)(b0+rq+r)*H_ + col2 + nf*16] = f2bf(fmaxf(acc[nf][r] + bb2[nf], 0.0f));
  } else {
    #pragma unroll
    for (int nf = 0; nf < 2; ++nf)
      #pragma unroll
      for (int r = 0; r < 4; ++r)
        capre[(size_t)(b0+rq+r)*H_ + (col2 + nf*16 - 128)] = acc[nf][r] + r0v[col2 + nf*16 - 128];
  }
}

// ---------------- x_recon (MFMA): out = hfin @ W2^T + b2 ----------------
__global__ __launch_bounds__(256) void k_xrecon_mfma(
    const ushort* __restrict__ hfin_bf, const ushort* __restrict__ W2bf,
    const float* __restrict__ b2, float* __restrict__ out){
  __shared__ __align__(16) ushort at[64*136];
  __shared__ __align__(16) ushort bt[128*136];
  const int tid = threadIdx.x, lane = tid & 63, w = tid >> 6;
  const int bm = blockIdx.x >> 5, bn = blockIdx.x & 31;
  const int row0 = bm*64, c0 = bn*128;
  const int l15 = lane & 15, kq8 = (lane >> 4)*8, rq = (lane >> 4)*4;
  { int r = tid >> 2, kq = (tid & 3)*32;
    const ushort* src = &hfin_bf[(size_t)(row0 + r)*H_ + kq];
    #pragma unroll
    for (int i = 0; i < 4; ++i) *(uint4*)&at[r*136 + kq + 8*i] = *(const uint4*)(src + 8*i);
  }
  { int n = tid >> 1, kh = (tid & 1)*64;
    const ushort* src = &W2bf[(size_t)(c0 + n)*H_ + kh];
    #pragma unroll
    for (int i = 0; i < 8; ++i) *(uint4*)&bt[n*136 + kh + 8*i] = *(const uint4*)(src + 8*i);
  }
  __syncthreads();
  f32x4_t acc[8] = {};
  #pragma unroll
  for (int k = 0; k < 4; ++k){
    short8_t a = *(const short8_t*)&at[(w*16 + l15)*136 + k*32 + kq8];
    #pragma unroll
    for (int nf = 0; nf < 8; ++nf){
      short8_t b = *(const short8_t*)&bt[(nf*16 + l15)*136 + k*32 + kq8];
      acc[nf] = MFMA16(a, b, acc[nf]);
    }
  }
  #pragma unroll
  for (int nf = 0; nf < 8; ++nf){
    int c = c0 + nf*16 + l15;
    float bbv = b2[c];
    #pragma unroll
    for (int r = 0; r < 4; ++r){
      int row = row0 + w*16 + rq + r;
      out[(size_t)row*XD_ + c] = acc[nf][r] + bbv;
    }
  }
}

// ---------------- per-row transformer tail -> y_pred ----------------
__device__ __forceinline__ float wsum64(float v){
  #pragma unroll
  for (int off = 32; off > 0; off >>= 1) v += __shfl_xor(v, off, 64);
  return v;
}

__global__ __launch_bounds__(256) void k_tail(
    const float* __restrict__ h1pre, const float* __restrict__ capre,
    const float* __restrict__ ln1g, const float* __restrict__ ln1b,
    const float* __restrict__ ln2g, const float* __restrict__ ln2b,
    const float* __restrict__ ln3g, const float* __restrict__ ln3b,
    const float* __restrict__ fW1, const float* __restrict__ fb1,
    const float* __restrict__ fW2, const float* __restrict__ fb2,
    const float* __restrict__ outW, const float* __restrict__ outb,
    float* __restrict__ y){
  __shared__ float sh2[4][128];
  __shared__ float st1[4][128];
  const int tid = threadIdx.x;
  const int w = tid >> 6;
  const int l = tid & 63;
  const int b = blockIdx.x * 4 + w;
  const float* hp = h1pre + (size_t)b * H_;
  const float* cp = capre + (size_t)b * H_;
  float x0 = hp[l], x1 = hp[l+64];
  float m = wsum64(x0 + x1) * (1.0f/128.0f);
  float d0 = x0 - m, d1 = x1 - m;
  float v = wsum64(d0*d0 + d1*d1) * (1.0f/128.0f);
  float rs = rsqrtf(v + 1e-5f);
  float h1a = d0 * rs * ln1g[l]    + ln1b[l];
  float h1b = d1 * rs * ln1g[l+64] + ln1b[l+64];
  x0 = h1a + cp[l]; x1 = h1b + cp[l+64];
  m = wsum64(x0 + x1) * (1.0f/128.0f);
  d0 = x0 - m; d1 = x1 - m;
  v = wsum64(d0*d0 + d1*d1) * (1.0f/128.0f);
  rs = rsqrtf(v + 1e-5f);
  float h2a = d0 * rs * ln2g[l]    + ln2b[l];
  float h2b = d1 * rs * ln2g[l+64] + ln2b[l+64];
  sh2[w][l] = h2a; sh2[w][l+64] = h2b;
  __syncthreads();
  float ta = fb1[l], tb = fb1[l+64];
  #pragma unroll 8
  for (int m4 = 0; m4 < H_; m4 += 4){
    float4 hv = *(const float4*)&sh2[w][m4];
    float4 wa = *(const float4*)&fW1[(size_t)l*H_ + m4];
    float4 wb = *(const float4*)&fW1[(size_t)(l+64)*H_ + m4];
    ta = fmaf(wa.x, hv.x, ta); ta = fmaf(wa.y, hv.y, ta); ta = fmaf(wa.z, hv.z, ta); ta = fmaf(wa.w, hv.w, ta);
    tb = fmaf(wb.x, hv.x, tb); tb = fmaf(wb.y, hv.y, tb); tb = fmaf(wb.z, hv.z, tb); tb = fmaf(wb.w, hv.w, tb);
  }
  ta = fmaxf(ta, 0.0f); tb = fmaxf(tb, 0.0f);
  st1[w][l] = ta; st1[w][l+64] = tb;
  __syncthreads();
  float fa = fb2[l], fbv = fb2[l+64];
  #pragma unroll 8
  for (int m4 = 0; m4 < H_; m4 += 4){
    float4 tv = *(const float4*)&st1[w][m4];
    float4 wa = *(const float4*)&fW2[(size_t)l*H_ + m4];
    float4 wb = *(const float4*)&fW2[(size_t)(l+64)*H_ + m4];
    fa  = fmaf(wa.x, tv.x, fa);  fa  = fmaf(wa.y, tv.y, fa);  fa  = fmaf(wa.z, tv.z, fa);  fa  = fmaf(wa.w, tv.w, fa);
    fbv = fmaf(wb.x, tv.x, fbv); fbv = fmaf(wb.y, tv.y, fbv); fbv = fmaf(wb.z, tv.z, fbv); fbv = fmaf(wb.w, tv.w, fbv);
  }
  x0 = h2a + fa; x1 = h2b + fbv;
  m = wsum64(x0 + x1) * (1.0f/128.0f);
  d0 = x0 - m; d1 = x1 - m;
  v = wsum64(d0*d0 + d1*d1) * (1.0f/128.0f);
  rs = rsqrtf(v + 1e-5f);
  float h3a = d0 * rs * ln3g[l]    + ln3b[l];
  float h3b = d1 * rs * ln3g[l+64] + ln3b[l+64];
  float py = wsum64(outW[l]*h3a + outW[l+64]*h3b);
  if (l == 0) y[b] = py + outb[0];
}

// ---------------- host ----------------
extern "C" void kernel_launch(void* const* d_in, const int* in_sizes, int n_in,
                              void* d_out, int out_size, void* d_ws, size_t ws_size,
                              hipStream_t stream){
  const float* x      = (const float*)d_in[0];
  const float* pxW1   = (const float*)d_in[1];
  const float* pxb1   = (const float*)d_in[2];
  const float* pxW2   = (const float*)d_in[3];
  const float* pxb2   = (const float*)d_in[4];
  const float* embW   = (const float*)d_in[5];
  const float* embb   = (const float*)d_in[6];
  const float* xpW    = (const float*)d_in[7];
  const float* xpb    = (const float*)d_in[8];
  const float* zpW    = (const float*)d_in[9];
  const float* zpb    = (const float*)d_in[10];
  const float* saWqkv = (const float*)d_in[11];
  const float* sabqkv = (const float*)d_in[12];
  const float* saWo   = (const float*)d_in[13];
  const float* sabo   = (const float*)d_in[14];
  const float* caWqkv = (const float*)d_in[15];
  const float* cabqkv = (const float*)d_in[16];
  const float* caWo   = (const float*)d_in[17];
  const float* cabo   = (const float*)d_in[18];
  const float* fW1    = (const float*)d_in[19];
  const float* fb1    = (const float*)d_in[20];
  const float* fW2    = (const float*)d_in[21];
  const float* fb2    = (const float*)d_in[22];
  const float* ln1g   = (const float*)d_in[23];
  const float* ln1b   = (const float*)d_in[24];
  const float* ln2g   = (const float*)d_in[25];
  const float* ln2b   = (const float*)d_in[26];
  const float* ln3g   = (const float*)d_in[27];
  const float* ln3b   = (const float*)d_in[28];
  const float* outW   = (const float*)d_in[29];
  const float* outb   = (const float*)d_in[30];
  (void)in_sizes; (void)n_in; (void)out_size; (void)ws_size;

  float* ws    = (float*)d_ws;
  float* cneg  = ws;                          // 1048576
  float* h1pre = cneg + (size_t)B_*H_;        // 1048576
  float* capre = h1pre + (size_t)B_*H_;       // 1048576
  float* Rm    = capre + (size_t)B_*H_;       // 131072
  float* Mm    = Rm + (size_t)H_*ZD_;         // 16384
  float* Sm    = Mm + H_*H_;                  // 16384
  float* Um    = Sm + H_*H_;                  // 16384
  float* Tm    = Um + H_*H_;                  // 8192
  float* vs0   = Tm + H_*XE_;
  float* vu0   = vs0 + H_;
  float* vt0   = vu0 + H_;
  float* vq0   = vt0 + H_;
  float* vr0   = vq0 + H_;
  float* vcb   = vr0 + H_;
  uint32_t* dkeys = (uint32_t*)(vcb + H_);    // 32 u32
  float* y0c0  = (float*)(dkeys + 32);        // 2097152 f32
  ushort* WXT   = (ushort*)(y0c0 + (size_t)B_*256);  // 1048576
  ushort* W2bf  = WXT + (size_t)256*XD_;      // 524288
  ushort* Mbf   = W2bf + (size_t)XD_*H_;      // 16384 (=2M)
  ushort* FBT   = Mbf + H_*H_;                // 262144
  ushort* GGr   = FBT + (size_t)256*ZD_;      // 32768
  ushort* hfin  = GGr + (size_t)256*H_;       // 1048576
  ushort* NWR   = hfin + (size_t)B_*H_;       // 20971520 (10 x 8192 x 256)

  float* xre   = (float*)d_out;
  float* ypred = xre + (size_t)B_*XD_;

  k_prepA   <<<512,  64, 0, stream>>>(saWo, saWqkv, caWo, caWqkv, Sm, Um);
  k_prepB   <<<6,    64, 0, stream>>>(saWo, sabqkv, sabo, caWo, cabqkv, cabo, pxW2, pxb2,
                                      vs0, vu0, vcb, dkeys);
  k_prepM   <<<256,  64, 0, stream>>>(pxW2, Mm);
  k_prepTR  <<<2180, 64, 0, stream>>>(Sm, Um, xpW, zpW, xpb, zpb, vs0, vu0, Tm, Rm, vt0, vr0);
  k_prepWXT <<<4096, 256, 0, stream>>>(pxW2, Tm, embW, embb, vt0, WXT, vq0);
  k_conv    <<<3136, 256, 0, stream>>>(pxW2, pxW1, Mm, Rm, W2bf, Mbf, FBT);
  k_prepG   <<<512,  64, 0, stream>>>(pxW1, Rm, GGr);
  k_noiseproj <<<1408, 256, 0, stream>>>(FBT, dkeys, y0c0, NWR);
  k_xpass_mfma <<<512, 256, 0, stream>>>(x, WXT, vcb, vq0, cneg, h1pre);
  k_lv2     <<<512, 512, 0, stream>>>(Mbf, GGr, y0c0, NWR, pxb1, vr0, cneg, hfin, capre);
  k_xrecon_mfma <<<4096, 256, 0, stream>>>(hfin, W2bf, pxb2, xre);
  k_tail    <<<2048, 256, 0, stream>>>(h1pre, capre, ln1g, ln1b, ln2g, ln2b, ln3g, ln3b,
                                       fW1, fb1, fW2, fb2, outW, outb, ypred);
}